// Round 1
// baseline (305.422 us; speedup 1.0000x reference)
//
#include <hip/hip_runtime.h>
#include <hip/hip_bf16.h>

// Problem constants (B=2, T=4096, D=1024, H=16, HD=64, W=16)
#define D_MODEL 1024
#define SEQ_T   4096
#define NBATCH  2
#define NHEADS  16
#define HEAD_D  64
#define WIN     16

typedef __attribute__((ext_vector_type(8))) short bf16x8;           // MFMA A/B frag (guide §3)
typedef __attribute__((ext_vector_type(8))) unsigned short u16x8;   // 16B bf16 load
typedef __attribute__((ext_vector_type(4))) float f32x4;            // MFMA C/D frag

__device__ __forceinline__ unsigned short f2bf(float f) {
  union { float f; unsigned int u; } v; v.f = f;
  unsigned int r = v.u + 0x7fffu + ((v.u >> 16) & 1u);  // RNE
  return (unsigned short)(r >> 16);
}
__device__ __forceinline__ float bf2f(unsigned short u) {
  union { unsigned int u; float f; } v; v.u = ((unsigned int)u) << 16;
  return v.f;
}

// ---------------------------------------------------------------- casts
__global__ __launch_bounds__(256) void cast_f32_bf16(const float4* __restrict__ src,
                                                     ushort* __restrict__ dst, int n4) {
  int i = blockIdx.x * 256 + threadIdx.x;
  if (i >= n4) return;
  float4 v = src[i];
  ushort4 o;
  o.x = f2bf(v.x); o.y = f2bf(v.y); o.z = f2bf(v.z); o.w = f2bf(v.w);
  *(ushort4*)(dst + (size_t)i * 4) = o;
}

// ---------------------------------------------------------------- GEMM (m97 structure)
// C[m,n] = sum_k A[m,k] * Bt[n,k];  A: MxK row-major bf16, Bt: NxK row-major bf16.
// 128x128 tile, BK=64, 256 threads = 4 waves (2x2), each wave 64x64 = 4x4 frags.
// EPI=0: store bf16 to Cb.  EPI=1: Cf[idx] = acc + resid[idx] (fp32).
template <int EPI>
__global__ __launch_bounds__(256) void gemm_bt(const ushort* __restrict__ A,
                                               const ushort* __restrict__ Bt,
                                               ushort* __restrict__ Cb,
                                               float* __restrict__ Cf,
                                               const float* __restrict__ resid,
                                               int M, int N, int K) {
  __shared__ ushort As[128 * 64];
  __shared__ ushort Bs[128 * 64];
  const int lane = threadIdx.x & 63;
  const int wave = threadIdx.x >> 6;
  const int m0 = blockIdx.y * 128;
  const int n0 = blockIdx.x * 128;
  const int wm = (wave >> 1) * 64;
  const int wn = (wave & 1) * 64;

  f32x4 acc[4][4];
#pragma unroll
  for (int i = 0; i < 4; ++i)
#pragma unroll
    for (int j = 0; j < 4; ++j) acc[i][j] = (f32x4){0.f, 0.f, 0.f, 0.f};

  const int lrow = lane >> 3;        // 0..7
  const int lcol = (lane & 7) * 8;   // 0..56 (chunk of 8 bf16 = 16B)

  for (int k0 = 0; k0 < K; k0 += 64) {
    // stage A tile (128x64 bf16 = 16KB): 16 segments of 1KB; seg = i*4 + wave.
    // LDS dest = wave-uniform base + lane*16 (m104) -> linear row-major [row][k].
#pragma unroll
    for (int i = 0; i < 4; ++i) {
      int seg = i * 4 + wave;
      int row = seg * 8 + lrow;
      const ushort* gp = A + (size_t)(m0 + row) * K + k0 + lcol;
      ushort* lp = As + seg * 512;  // bytes: seg*1024 (uniform per wave-call)
      __builtin_amdgcn_global_load_lds((const __attribute__((address_space(1))) void*)gp,
                                       (__attribute__((address_space(3))) void*)lp, 16, 0, 0);
    }
#pragma unroll
    for (int i = 0; i < 4; ++i) {
      int seg = i * 4 + wave;
      int row = seg * 8 + lrow;
      const ushort* gp = Bt + (size_t)(n0 + row) * K + k0 + lcol;
      ushort* lp = Bs + seg * 512;
      __builtin_amdgcn_global_load_lds((const __attribute__((address_space(1))) void*)gp,
                                       (__attribute__((address_space(3))) void*)lp, 16, 0, 0);
    }
    __syncthreads();  // compiler drains vmcnt before s_barrier

#pragma unroll
    for (int kk = 0; kk < 64; kk += 32) {
      const int fr = lane & 15;
      const int fk = (lane >> 4) * 8 + kk;
      bf16x8 a[4], b[4];
#pragma unroll
      for (int mi = 0; mi < 4; ++mi)
        a[mi] = *(const bf16x8*)&As[(wm + mi * 16 + fr) * 64 + fk];
#pragma unroll
      for (int ni = 0; ni < 4; ++ni)
        b[ni] = *(const bf16x8*)&Bs[(wn + ni * 16 + fr) * 64 + fk];
#pragma unroll
      for (int mi = 0; mi < 4; ++mi)
#pragma unroll
        for (int ni = 0; ni < 4; ++ni)
          acc[mi][ni] = __builtin_amdgcn_mfma_f32_16x16x32_bf16(a[mi], b[ni], acc[mi][ni], 0, 0, 0);
    }
    __syncthreads();
  }

  // epilogue: C/D layout col = lane&15, row = (lane>>4)*4 + r   (m89/m91 verified)
  const int cc = lane & 15;
  const int cr = (lane >> 4) * 4;
#pragma unroll
  for (int mi = 0; mi < 4; ++mi) {
#pragma unroll
    for (int ni = 0; ni < 4; ++ni) {
#pragma unroll
      for (int r = 0; r < 4; ++r) {
        int row = m0 + wm + mi * 16 + cr + r;
        int col = n0 + wn + ni * 16 + cc;
        size_t idx = (size_t)row * N + col;
        float v = acc[mi][ni][r];
        if (EPI == 0) {
          Cb[idx] = f2bf(v);
        } else {
          Cf[idx] = v + resid[idx];
        }
      }
    }
  }
}

// ---------------------------------------------------------------- sliding-window attention
// qkv row layout (3072 bf16): [0..1023]=q (h*64+d), [1024..3071]=kv (h*128 + c; c<64:k, c>=64:v)
// One block per (b, h, 64-t tile). Stage kv rows [t0-16, t0+63] for this head to LDS (f32).
// One wave per t (4 waves x 16 t each): lane d; 16x {64-lane dot, sigmoid, fma}.
__global__ __launch_bounds__(256) void attn_win(const ushort* __restrict__ qkv,
                                                ushort* __restrict__ msg) {
  __shared__ float kvs[80][128];  // 40KB
  const int tile = blockIdx.x;    // 0..63
  const int h = blockIdx.y;
  const int b = blockIdx.z;
  const int t0 = tile * 64;
  const size_t rowbase = (size_t)b * SEQ_T;
  const int tid = threadIdx.x;

  // stage: 80 rows x 128 cols = 1280 chunks of 8 bf16
  for (int chunk = tid; chunk < 1280; chunk += 256) {
    int r = chunk >> 4;
    int c = (chunk & 15) * 8;
    int t = t0 - 16 + r;
    if (t >= 0) {
      const ushort* gp = qkv + (rowbase + t) * 3072 + 1024 + (size_t)h * 128 + c;
      u16x8 u = *(const u16x8*)gp;
#pragma unroll
      for (int j = 0; j < 8; ++j) kvs[r][c + j] = bf2f(u[j]);
    } else {
#pragma unroll
      for (int j = 0; j < 8; ++j) kvs[r][c + j] = 0.f;
    }
  }
  __syncthreads();

  const int wave = tid >> 6;
  const int lane = tid & 63;
#pragma unroll 1
  for (int i = 0; i < 16; ++i) {
    int t = t0 + wave * 16 + i;
    float qd = bf2f(qkv[(rowbase + t) * 3072 + (size_t)h * 64 + lane]);
    float msgd = 0.f;
    int lr0 = t - t0 + 15;  // local row of t-1
#pragma unroll
    for (int w = 0; w < WIN; ++w) {
      if (t - 1 - w < 0) break;  // wave-uniform; remaining w also invalid (v=0 in ref)
      int r = lr0 - w;
      float p = qd * kvs[r][lane];
      p += __shfl_xor(p, 1);
      p += __shfl_xor(p, 2);
      p += __shfl_xor(p, 4);
      p += __shfl_xor(p, 8);
      p += __shfl_xor(p, 16);
      p += __shfl_xor(p, 32);
      float tau = 1.f / (1.f + __expf(-p * 0.125f));  // /sqrt(64)
      msgd = fmaf(tau, kvs[r][64 + lane], msgd);
    }
    msg[(rowbase + t) * 1024 + (size_t)h * 64 + lane] = f2bf(msgd);
  }
}

// ---------------------------------------------------------------- in-place LayerNorm (row=1024)
__global__ __launch_bounds__(256) void layernorm_inplace(float* __restrict__ y,
                                                         const float* __restrict__ gamma,
                                                         const float* __restrict__ beta) {
  const int row = blockIdx.x;
  float* p = y + (size_t)row * D_MODEL;
  const int tid = threadIdx.x;
  float4 v = *(const float4*)&p[tid * 4];
  float s = v.x + v.y + v.z + v.w;
  float s2 = v.x * v.x + v.y * v.y + v.z * v.z + v.w * v.w;
#pragma unroll
  for (int m = 1; m < 64; m <<= 1) {
    s += __shfl_xor(s, m);
    s2 += __shfl_xor(s2, m);
  }
  __shared__ float red[8];
  const int wave = tid >> 6, lane = tid & 63;
  if (lane == 0) { red[wave] = s; red[4 + wave] = s2; }
  __syncthreads();
  s = red[0] + red[1] + red[2] + red[3];
  s2 = red[4] + red[5] + red[6] + red[7];
  const float mu = s * (1.f / D_MODEL);
  const float var = s2 * (1.f / D_MODEL) - mu * mu;
  const float rstd = rsqrtf(var + 1e-5f);
  float4 g = *(const float4*)&gamma[tid * 4];
  float4 be = *(const float4*)&beta[tid * 4];
  float4 o;
  o.x = (v.x - mu) * rstd * g.x + be.x;
  o.y = (v.y - mu) * rstd * g.y + be.y;
  o.z = (v.z - mu) * rstd * g.z + be.z;
  o.w = (v.w - mu) * rstd * g.w + be.w;
  *(float4*)&p[tid * 4] = o;
}

// ---------------------------------------------------------------- launch
extern "C" void kernel_launch(void* const* d_in, const int* in_sizes, int n_in,
                              void* d_out, int out_size, void* d_ws, size_t ws_size,
                              hipStream_t stream) {
  (void)in_sizes; (void)n_in; (void)out_size; (void)ws_size;
  const float* x = (const float*)d_in[0];
  const float* wq = (const float*)d_in[1];
  const float* wkv = (const float*)d_in[2];
  const float* wo = (const float*)d_in[3];
  const float* gamma = (const float*)d_in[4];
  const float* beta = (const float*)d_in[5];
  float* out = (float*)d_out;

  // workspace layout (bf16 buffers), total ~92.3 MB
  ushort* xb = (ushort*)d_ws;                          // 8192x1024
  ushort* wb = xb + (size_t)8192 * 1024;               // 4096x1024: [wq;wkv;wo]
  ushort* qkvb = wb + (size_t)4096 * 1024;             // 8192x3072
  ushort* msgb = qkvb + (size_t)8192 * 3072;           // 8192x1024

  const int M = NBATCH * SEQ_T;  // 8192

  cast_f32_bf16<<<(M * D_MODEL / 4 + 255) / 256, 256, 0, stream>>>((const float4*)x, xb, M * D_MODEL / 4);
  cast_f32_bf16<<<1024, 256, 0, stream>>>((const float4*)wq, wb, 262144);
  cast_f32_bf16<<<2048, 256, 0, stream>>>((const float4*)wkv, wb + (size_t)1024 * 1024, 524288);
  cast_f32_bf16<<<1024, 256, 0, stream>>>((const float4*)wo, wb + (size_t)3072 * 1024, 262144);

  // GEMM1: qkv = x @ [wq;wkv]^T   (M=8192, N=3072, K=1024), bf16 out
  gemm_bt<0><<<dim3(3072 / 128, M / 128), 256, 0, stream>>>(xb, wb, qkvb, nullptr, nullptr,
                                                            M, 3072, 1024);
  // windowed sigmoid attention -> msg (bf16)
  attn_win<<<dim3(SEQ_T / 64, NHEADS, NBATCH), 256, 0, stream>>>(qkvb, msgb);

  // GEMM2: y = x + msg @ wo^T  -> d_out (fp32)
  gemm_bt<1><<<dim3(1024 / 128, M / 128), 256, 0, stream>>>(msgb, wb + (size_t)3072 * 1024,
                                                            nullptr, out, x, M, 1024, 1024);
  // LayerNorm in place on d_out
  layernorm_inplace<<<M, 256, 0, stream>>>(out, gamma, beta);
}

// Round 2
// 158.689 us; speedup vs baseline: 1.9247x; 1.9247x over previous
//
#include <hip/hip_runtime.h>
#include <hip/hip_bf16.h>

// Problem constants (B=2, T=4096, D=1024, H=16, HD=64, W=16)
#define D_MODEL 1024
#define SEQ_T   4096
#define NBATCH  2
#define NHEADS  16
#define HEAD_D  64
#define WIN     16

typedef __attribute__((ext_vector_type(8))) short bf16x8;           // MFMA A/B frag (guide §3)
typedef __attribute__((ext_vector_type(8))) unsigned short u16x8;   // 16B bf16 load
typedef __attribute__((ext_vector_type(4))) float f32x4;            // MFMA C/D frag

__device__ __forceinline__ unsigned short f2bf(float f) {
  union { float f; unsigned int u; } v; v.f = f;
  unsigned int r = v.u + 0x7fffu + ((v.u >> 16) & 1u);  // RNE
  return (unsigned short)(r >> 16);
}
__device__ __forceinline__ float bf2f(unsigned short u) {
  union { unsigned int u; float f; } v; v.u = ((unsigned int)u) << 16;
  return v.f;
}

// ---------------------------------------------------------------- casts
__global__ __launch_bounds__(256) void cast_f32_bf16(const float4* __restrict__ src,
                                                     ushort* __restrict__ dst, int n4) {
  int i = blockIdx.x * 256 + threadIdx.x;
  if (i >= n4) return;
  float4 v = src[i];
  ushort4 o;
  o.x = f2bf(v.x); o.y = f2bf(v.y); o.z = f2bf(v.z); o.w = f2bf(v.w);
  *(ushort4*)(dst + (size_t)i * 4) = o;
}

// ---------------------------------------------------------------- GEMM (m97 structure)
// C[m,n] = sum_k A[m,k] * Bt[n,k];  A: MxK row-major bf16, Bt: NxK row-major bf16.
// 128x128 tile, BK=64, 256 threads = 4 waves (2x2), each wave 64x64 = 4x4 frags.
// EPI=0: store bf16 to Cb.  EPI=1: Cf[idx] = acc + resid[idx] (fp32).
template <int EPI>
__global__ __launch_bounds__(256) void gemm_bt(const ushort* __restrict__ A,
                                               const ushort* __restrict__ Bt,
                                               ushort* __restrict__ Cb,
                                               float* __restrict__ Cf,
                                               const float* __restrict__ resid,
                                               int M, int N, int K) {
  __shared__ ushort As[128 * 64];
  __shared__ ushort Bs[128 * 64];
  const int lane = threadIdx.x & 63;
  const int wave = threadIdx.x >> 6;
  const int m0 = blockIdx.y * 128;
  const int n0 = blockIdx.x * 128;
  const int wm = (wave >> 1) * 64;
  const int wn = (wave & 1) * 64;

  f32x4 acc[4][4];
#pragma unroll
  for (int i = 0; i < 4; ++i)
#pragma unroll
    for (int j = 0; j < 4; ++j) acc[i][j] = (f32x4){0.f, 0.f, 0.f, 0.f};

  const int lrow = lane >> 3;        // 0..7
  const int lcol = (lane & 7) * 8;   // 0..56 (chunk of 8 bf16 = 16B)

  for (int k0 = 0; k0 < K; k0 += 64) {
#pragma unroll
    for (int i = 0; i < 4; ++i) {
      int seg = i * 4 + wave;
      int row = seg * 8 + lrow;
      const ushort* gp = A + (size_t)(m0 + row) * K + k0 + lcol;
      ushort* lp = As + seg * 512;
      __builtin_amdgcn_global_load_lds((const __attribute__((address_space(1))) void*)gp,
                                       (__attribute__((address_space(3))) void*)lp, 16, 0, 0);
    }
#pragma unroll
    for (int i = 0; i < 4; ++i) {
      int seg = i * 4 + wave;
      int row = seg * 8 + lrow;
      const ushort* gp = Bt + (size_t)(n0 + row) * K + k0 + lcol;
      ushort* lp = Bs + seg * 512;
      __builtin_amdgcn_global_load_lds((const __attribute__((address_space(1))) void*)gp,
                                       (__attribute__((address_space(3))) void*)lp, 16, 0, 0);
    }
    __syncthreads();

#pragma unroll
    for (int kk = 0; kk < 64; kk += 32) {
      const int fr = lane & 15;
      const int fk = (lane >> 4) * 8 + kk;
      bf16x8 a[4], b[4];
#pragma unroll
      for (int mi = 0; mi < 4; ++mi)
        a[mi] = *(const bf16x8*)&As[(wm + mi * 16 + fr) * 64 + fk];
#pragma unroll
      for (int ni = 0; ni < 4; ++ni)
        b[ni] = *(const bf16x8*)&Bs[(wn + ni * 16 + fr) * 64 + fk];
#pragma unroll
      for (int mi = 0; mi < 4; ++mi)
#pragma unroll
        for (int ni = 0; ni < 4; ++ni)
          acc[mi][ni] = __builtin_amdgcn_mfma_f32_16x16x32_bf16(a[mi], b[ni], acc[mi][ni], 0, 0, 0);
    }
    __syncthreads();
  }

  const int cc = lane & 15;
  const int cr = (lane >> 4) * 4;
#pragma unroll
  for (int mi = 0; mi < 4; ++mi) {
#pragma unroll
    for (int ni = 0; ni < 4; ++ni) {
#pragma unroll
      for (int r = 0; r < 4; ++r) {
        int row = m0 + wm + mi * 16 + cr + r;
        int col = n0 + wn + ni * 16 + cc;
        size_t idx = (size_t)row * N + col;
        float v = acc[mi][ni][r];
        if (EPI == 0) {
          Cb[idx] = f2bf(v);
        } else {
          Cf[idx] = v + resid[idx];
        }
      }
    }
  }
}

// ---------------------------------------------------------------- sliding-window attention (MFMA band)
// One block per (b, h, 64-t tile). 4 waves; wave w owns t-subtile [t0+w*16, t0+w*16+15].
// S(16x32) = Q @ K_span^T (4 MFMA) -> band mask + sigmoid in-register ->
// P via LDS to A-frag layout -> msg(16x64) = P @ V_span (4 MFMA).
__global__ __launch_bounds__(256) void attn_win_mfma(const ushort* __restrict__ qkv,
                                                     ushort* __restrict__ msg) {
  __shared__ ushort Ks[80][72];     // K [r][d], r -> t0-16+r; stride 144B (16B-aligned)
  __shared__ ushort Vt[64][88];     // V^T [d][r]; stride 176B (16B-aligned)
  __shared__ ushort Ps[4][16][40];  // per-wave P [t][r_local]; stride 80B

  const int tile = blockIdx.x;
  const int h = blockIdx.y;
  const int b = blockIdx.z;
  const int t0 = tile * 64;
  const size_t rowbase = (size_t)b * SEQ_T;
  const int tid = threadIdx.x;
  const int wave = tid >> 6;
  const int lane = tid & 63;

  // stage K (natural) and V (transposed): 80 rows x 16 chunks of 8 bf16
  for (int chunk = tid; chunk < 1280; chunk += 256) {
    int r = chunk >> 4;
    int c = (chunk & 15) * 8;
    int t = t0 - 16 + r;
    u16x8 u = {0, 0, 0, 0, 0, 0, 0, 0};
    if (t >= 0)
      u = *(const u16x8*)(qkv + (rowbase + t) * 3072 + 1024 + (size_t)h * 128 + c);
    if (c < 64) {
      *(u16x8*)&Ks[r][c] = u;
    } else {
      int d0 = c - 64;
#pragma unroll
      for (int j = 0; j < 8; ++j) Vt[d0 + j][r] = u[j];
    }
  }
  __syncthreads();

  const int fr = lane & 15;
  const int g = lane >> 4;
  const int rbase = wave * 16;

  // Q A-frags from global: row t0+wave*16+fr, k = kk*32 + g*8 + j
  bf16x8 qa[2];
#pragma unroll
  for (int kk = 0; kk < 2; ++kk)
    qa[kk] = *(const bf16x8*)(qkv + (rowbase + t0 + wave * 16 + fr) * 3072 +
                              (size_t)h * 64 + kk * 32 + g * 8);

  // S = Q @ K^T
  f32x4 sacc[2];
  sacc[0] = (f32x4){0.f, 0.f, 0.f, 0.f};
  sacc[1] = (f32x4){0.f, 0.f, 0.f, 0.f};
#pragma unroll
  for (int kk = 0; kk < 2; ++kk) {
#pragma unroll
    for (int nt = 0; nt < 2; ++nt) {
      bf16x8 kb = *(const bf16x8*)&Ks[rbase + nt * 16 + fr][kk * 32 + g * 8];
      sacc[nt] = __builtin_amdgcn_mfma_f32_16x16x32_bf16(qa[kk], kb, sacc[nt], 0, 0, 0);
    }
  }

  // band mask + sigmoid -> Ps   (acc: col=lane&15 -> r, row=(lane>>4)*4+reg -> t)
#pragma unroll
  for (int nt = 0; nt < 2; ++nt) {
    int tk = t0 - 16 + rbase + nt * 16 + fr;
#pragma unroll
    for (int reg = 0; reg < 4; ++reg) {
      int t = t0 + wave * 16 + g * 4 + reg;
      float tau = 0.f;
      if (tk >= 0 && tk >= t - WIN && tk <= t - 1)
        tau = 1.f / (1.f + __expf(-sacc[nt][reg] * 0.125f));
      Ps[wave][g * 4 + reg][nt * 16 + fr] = f2bf(tau);
    }
  }
  __syncthreads();

  // msg = P @ V  (K=32 single step)
  bf16x8 pa = *(const bf16x8*)&Ps[wave][fr][g * 8];
#pragma unroll
  for (int ct = 0; ct < 4; ++ct) {
    bf16x8 vb = *(const bf16x8*)&Vt[ct * 16 + fr][rbase + g * 8];
    f32x4 m = __builtin_amdgcn_mfma_f32_16x16x32_bf16(pa, vb, (f32x4){0.f, 0.f, 0.f, 0.f}, 0, 0, 0);
#pragma unroll
    for (int reg = 0; reg < 4; ++reg) {
      int t = t0 + wave * 16 + g * 4 + reg;
      msg[(rowbase + t) * 1024 + (size_t)h * 64 + ct * 16 + fr] = f2bf(m[reg]);
    }
  }
}

// ---------------------------------------------------------------- in-place LayerNorm (row=1024)
__global__ __launch_bounds__(256) void layernorm_inplace(float* __restrict__ y,
                                                         const float* __restrict__ gamma,
                                                         const float* __restrict__ beta) {
  const int row = blockIdx.x;
  float* p = y + (size_t)row * D_MODEL;
  const int tid = threadIdx.x;
  float4 v = *(const float4*)&p[tid * 4];
  float s = v.x + v.y + v.z + v.w;
  float s2 = v.x * v.x + v.y * v.y + v.z * v.z + v.w * v.w;
#pragma unroll
  for (int m = 1; m < 64; m <<= 1) {
    s += __shfl_xor(s, m);
    s2 += __shfl_xor(s2, m);
  }
  __shared__ float red[8];
  const int wave = tid >> 6, lane = tid & 63;
  if (lane == 0) { red[wave] = s; red[4 + wave] = s2; }
  __syncthreads();
  s = red[0] + red[1] + red[2] + red[3];
  s2 = red[4] + red[5] + red[6] + red[7];
  const float mu = s * (1.f / D_MODEL);
  const float var = s2 * (1.f / D_MODEL) - mu * mu;
  const float rstd = rsqrtf(var + 1e-5f);
  float4 g = *(const float4*)&gamma[tid * 4];
  float4 be = *(const float4*)&beta[tid * 4];
  float4 o;
  o.x = (v.x - mu) * rstd * g.x + be.x;
  o.y = (v.y - mu) * rstd * g.y + be.y;
  o.z = (v.z - mu) * rstd * g.z + be.z;
  o.w = (v.w - mu) * rstd * g.w + be.w;
  *(float4*)&p[tid * 4] = o;
}

// ---------------------------------------------------------------- launch
extern "C" void kernel_launch(void* const* d_in, const int* in_sizes, int n_in,
                              void* d_out, int out_size, void* d_ws, size_t ws_size,
                              hipStream_t stream) {
  (void)in_sizes; (void)n_in; (void)out_size; (void)ws_size;
  const float* x = (const float*)d_in[0];
  const float* wq = (const float*)d_in[1];
  const float* wkv = (const float*)d_in[2];
  const float* wo = (const float*)d_in[3];
  const float* gamma = (const float*)d_in[4];
  const float* beta = (const float*)d_in[5];
  float* out = (float*)d_out;

  ushort* xb = (ushort*)d_ws;                          // 8192x1024
  ushort* wb = xb + (size_t)8192 * 1024;               // 4096x1024: [wq;wkv;wo]
  ushort* qkvb = wb + (size_t)4096 * 1024;             // 8192x3072
  ushort* msgb = qkvb + (size_t)8192 * 3072;           // 8192x1024

  const int M = NBATCH * SEQ_T;  // 8192

  cast_f32_bf16<<<(M * D_MODEL / 4 + 255) / 256, 256, 0, stream>>>((const float4*)x, xb, M * D_MODEL / 4);
  cast_f32_bf16<<<1024, 256, 0, stream>>>((const float4*)wq, wb, 262144);
  cast_f32_bf16<<<2048, 256, 0, stream>>>((const float4*)wkv, wb + (size_t)1024 * 1024, 524288);
  cast_f32_bf16<<<1024, 256, 0, stream>>>((const float4*)wo, wb + (size_t)3072 * 1024, 262144);

  // GEMM1: qkv = x @ [wq;wkv]^T   (M=8192, N=3072, K=1024), bf16 out
  gemm_bt<0><<<dim3(3072 / 128, M / 128), 256, 0, stream>>>(xb, wb, qkvb, nullptr, nullptr,
                                                            M, 3072, 1024);
  // windowed sigmoid attention -> msg (bf16), MFMA band formulation
  attn_win_mfma<<<dim3(SEQ_T / 64, NHEADS, NBATCH), 256, 0, stream>>>(qkvb, msgb);

  // GEMM2: y = x + msg @ wo^T  -> d_out (fp32)
  gemm_bt<1><<<dim3(1024 / 128, M / 128), 256, 0, stream>>>(msgb, wb + (size_t)3072 * 1024,
                                                            nullptr, out, x, M, 1024, 1024);
  // LayerNorm in place on d_out
  layernorm_inplace<<<M, 256, 0, stream>>>(out, gamma, beta);
}

// Round 3
// 143.450 us; speedup vs baseline: 2.1291x; 1.1062x over previous
//
#include <hip/hip_runtime.h>
#include <hip/hip_bf16.h>

// Problem constants (B=2, T=4096, D=1024, H=16, HD=64, W=16)
#define D_MODEL 1024
#define SEQ_T   4096
#define NBATCH  2
#define NHEADS  16
#define HEAD_D  64
#define WIN     16

typedef __attribute__((ext_vector_type(8))) short bf16x8;           // MFMA A/B frag
typedef __attribute__((ext_vector_type(8))) unsigned short u16x8;   // 16B bf16 load
typedef __attribute__((ext_vector_type(4))) float f32x4;            // MFMA C/D frag

__device__ __forceinline__ unsigned short f2bf(float f) {
  union { float f; unsigned int u; } v; v.f = f;
  unsigned int r = v.u + 0x7fffu + ((v.u >> 16) & 1u);  // RNE
  return (unsigned short)(r >> 16);
}
__device__ __forceinline__ float bf2f(unsigned short u) {
  union { unsigned int u; float f; } v; v.u = ((unsigned int)u) << 16;
  return v.f;
}

// ---------------------------------------------------------------- casts
__global__ __launch_bounds__(256) void cast_f32_bf16(const float4* __restrict__ src,
                                                     ushort* __restrict__ dst, int n4) {
  int i = blockIdx.x * 256 + threadIdx.x;
  if (i >= n4) return;
  float4 v = src[i];
  ushort4 o;
  o.x = f2bf(v.x); o.y = f2bf(v.y); o.z = f2bf(v.z); o.w = f2bf(v.w);
  *(ushort4*)(dst + (size_t)i * 4) = o;
}

// ---------------------------------------------------------------- 8-phase 256x256 GEMM (T2+T3+T4+T5)
// C[m,n] = sum_k A[m,k]*Bt[n,k]; A MxK, Bt NxK row-major bf16; C bf16.
// 512 thr = 8 waves (2 Mrows x 4 Ncols); per-wave per-quadrant 64x32.
// LDS 128KiB: A[dbuf][half][128][64], B likewise at +64KiB. BK=64, NTK=K/64.
// Swizzle (both-sides, rule 21): 16B-chunk ^= (row&7); source pre-swizzled, reads swizzled.
#define SBAR() __builtin_amdgcn_s_barrier()
#define FENCE() __builtin_amdgcn_sched_barrier(0)
#define LGKM0() asm volatile("s_waitcnt lgkmcnt(0)" ::: "memory")
#define VMC6() asm volatile("s_waitcnt vmcnt(6)" ::: "memory")

__global__ __launch_bounds__(512, 2) void gemm1_8ph(const ushort* __restrict__ A,
                                                    const ushort* __restrict__ Bt,
                                                    ushort* __restrict__ C,
                                                    int M, int N, int K) {
  extern __shared__ char smem[];  // 131072 bytes
  const int NTK = K >> 6;
  const int tid = threadIdx.x;
  const int wid = tid >> 6;
  const int lane = tid & 63;
  const int m0 = blockIdx.y * 256;
  const int n0 = blockIdx.x * 256;

  // staging lane geometry (pre-swizzled source chunk)
  const int l8 = lane >> 3;                    // row within 8-row segment
  const int lchunk = (lane & 7) ^ (l8 & 7);    // logical 16B chunk to fetch
  const ushort* pA = A + (size_t)(m0 + wid * 16 + l8) * K + lchunk * 8;
  const ushort* pB = Bt + (size_t)(n0 + wid * 16 + l8) * K + lchunk * 8;

// stage one half-tile (128 rows x 64 k) of array X into buf db, half h, k-tile kt.
// LDS dest: base + db*32768 + h*16384 + seg*1024 (linear); seg = wid*2+j.
#define STAGE_A(h, kt, db)                                                                 \
  {                                                                                        \
    _Pragma("unroll") for (int j = 0; j < 2; ++j) {                                        \
      const ushort* gp = pA + (size_t)((h) * 128 + j * 8) * K + (size_t)(kt) * 64;         \
      char* lp = smem + (db) * 32768 + (h) * 16384 + (wid * 2 + j) * 1024;                 \
      __builtin_amdgcn_global_load_lds((const __attribute__((address_space(1))) void*)gp,  \
                                       (__attribute__((address_space(3))) void*)lp, 16, 0, 0); \
    }                                                                                      \
  }
#define STAGE_B(h, kt, db)                                                                 \
  {                                                                                        \
    _Pragma("unroll") for (int j = 0; j < 2; ++j) {                                        \
      const ushort* gp = pB + (size_t)((h) * 128 + j * 8) * K + (size_t)(kt) * 64;         \
      char* lp = smem + 65536 + (db) * 32768 + (h) * 16384 + (wid * 2 + j) * 1024;         \
      __builtin_amdgcn_global_load_lds((const __attribute__((address_space(1))) void*)gp,  \
                                       (__attribute__((address_space(3))) void*)lp, 16, 0, 0); \
    }                                                                                      \
  }

  // compute-side lane geometry
  const int fr = lane & 15;
  const int g = lane >> 4;
  const int wr = wid >> 2;   // 0..1
  const int wc = wid & 3;    // 0..3
  const int swz = fr & 7;
  // per-lane constant byte offsets
  int aRow[4], bRow[2], ch[2];
#pragma unroll
  for (int mi = 0; mi < 4; ++mi) aRow[mi] = (wr * 64 + mi * 16 + fr) * 128;
#pragma unroll
  for (int ni = 0; ni < 2; ++ni) bRow[ni] = (wc * 32 + ni * 16 + fr) * 128;
#pragma unroll
  for (int kk = 0; kk < 2; ++kk) ch[kk] = ((kk * 4 + g) ^ swz) * 16;

  f32x4 acc[2][2][4][2];
#pragma unroll
  for (int mq = 0; mq < 2; ++mq)
#pragma unroll
    for (int nq = 0; nq < 2; ++nq)
#pragma unroll
      for (int mi = 0; mi < 4; ++mi)
#pragma unroll
        for (int ni = 0; ni < 2; ++ni) acc[mq][nq][mi][ni] = (f32x4){0.f, 0.f, 0.f, 0.f};

  bf16x8 a[4][2], bf[2][2][2];

  // ---- prologue: tile0 (A0,B0,B1,A1) + tile1 (A0,B0,B1); leaves 6 loads in flight
  STAGE_A(0, 0, 0); STAGE_B(0, 0, 0); STAGE_B(1, 0, 0); STAGE_A(1, 0, 0);
  STAGE_A(0, 1, 1); STAGE_B(0, 1, 1); STAGE_B(1, 1, 1);
  VMC6();
  FENCE(); SBAR();

#define PHASE_MFMA(mq, nq)                                                     \
  __builtin_amdgcn_s_setprio(1);                                               \
  _Pragma("unroll") for (int mi = 0; mi < 4; ++mi)                             \
    _Pragma("unroll") for (int ni = 0; ni < 2; ++ni)                           \
      _Pragma("unroll") for (int kk = 0; kk < 2; ++kk)                         \
        acc[mq][nq][mi][ni] = __builtin_amdgcn_mfma_f32_16x16x32_bf16(         \
            a[mi][kk], bf[nq][ni][kk], acc[mq][nq][mi][ni], 0, 0, 0);          \
  __builtin_amdgcn_s_setprio(0);

#pragma unroll 1
  for (int t = 0; t < NTK; ++t) {
    const int db = t & 1;
    const int u1 = (t + 1 < NTK) ? t + 1 : NTK - 1;
    const int u2 = (t + 2 < NTK) ? t + 2 : NTK - 1;
    const int d1 = u1 & 1, d2 = u2 & 1;
    const char* Ab = smem + db * 32768;
    const char* Bb = smem + 65536 + db * 32768;

    // ---- P0 (mq=0,nq=0): read A-half0 (8) + B-half0 (4); stage A1(t+1)
#pragma unroll
    for (int mi = 0; mi < 4; ++mi)
#pragma unroll
      for (int kk = 0; kk < 2; ++kk)
        a[mi][kk] = *(const bf16x8*)(Ab + 0 * 16384 + aRow[mi] + ch[kk]);
#pragma unroll
    for (int ni = 0; ni < 2; ++ni)
#pragma unroll
      for (int kk = 0; kk < 2; ++kk)
        bf[0][ni][kk] = *(const bf16x8*)(Bb + 0 * 16384 + bRow[ni] + ch[kk]);
    STAGE_A(1, u1, d1);
    FENCE(); SBAR(); LGKM0(); FENCE();
    PHASE_MFMA(0, 0);
    FENCE(); SBAR();

    // ---- P1 (0,1): read B-half1 (4); stage A0(t+2)  [A0 region freed at P0 barrier]
#pragma unroll
    for (int ni = 0; ni < 2; ++ni)
#pragma unroll
      for (int kk = 0; kk < 2; ++kk)
        bf[1][ni][kk] = *(const bf16x8*)(Bb + 1 * 16384 + bRow[ni] + ch[kk]);
    STAGE_A(0, u2, d2);
    FENCE(); SBAR(); LGKM0(); FENCE();
    PHASE_MFMA(0, 1);
    FENCE(); SBAR();

    // ---- P2 (1,0): read A-half1 (8); stage B0(t+2)  [B0 freed at P0]
#pragma unroll
    for (int mi = 0; mi < 4; ++mi)
#pragma unroll
      for (int kk = 0; kk < 2; ++kk)
        a[mi][kk] = *(const bf16x8*)(Ab + 1 * 16384 + aRow[mi] + ch[kk]);
    STAGE_B(0, u2, d2);
    FENCE(); SBAR(); LGKM0(); FENCE();
    PHASE_MFMA(1, 0);
    FENCE(); SBAR();

    // ---- P3 (1,1): no reads; stage B1(t+2) [B1 freed at P1]; counted vmcnt
    STAGE_B(1, u2, d2);
    VMC6();
    FENCE(); SBAR(); LGKM0(); FENCE();
    PHASE_MFMA(1, 1);
    FENCE(); SBAR();
  }

  // ---- epilogue: C/D layout col=lane&15, row=(lane>>4)*4+r
  const int cc = lane & 15;
  const int cr4 = (lane >> 4) * 4;
#pragma unroll
  for (int mq = 0; mq < 2; ++mq)
#pragma unroll
    for (int nq = 0; nq < 2; ++nq)
#pragma unroll
      for (int mi = 0; mi < 4; ++mi)
#pragma unroll
        for (int ni = 0; ni < 2; ++ni)
#pragma unroll
          for (int r = 0; r < 4; ++r) {
            int row = m0 + mq * 128 + wr * 64 + mi * 16 + cr4 + r;
            int col = n0 + nq * 128 + wc * 32 + ni * 16 + cc;
            C[(size_t)row * N + col] = f2bf(acc[mq][nq][mi][ni][r]);
          }
#undef STAGE_A
#undef STAGE_B
#undef PHASE_MFMA
}

// ---------------------------------------------------------------- GEMM (m97 structure, used for GEMM2)
template <int EPI>
__global__ __launch_bounds__(256) void gemm_bt(const ushort* __restrict__ A,
                                               const ushort* __restrict__ Bt,
                                               ushort* __restrict__ Cb,
                                               float* __restrict__ Cf,
                                               const float* __restrict__ resid,
                                               int M, int N, int K) {
  __shared__ ushort As[128 * 64];
  __shared__ ushort Bs[128 * 64];
  const int lane = threadIdx.x & 63;
  const int wave = threadIdx.x >> 6;
  const int m0 = blockIdx.y * 128;
  const int n0 = blockIdx.x * 128;
  const int wm = (wave >> 1) * 64;
  const int wn = (wave & 1) * 64;

  f32x4 acc[4][4];
#pragma unroll
  for (int i = 0; i < 4; ++i)
#pragma unroll
    for (int j = 0; j < 4; ++j) acc[i][j] = (f32x4){0.f, 0.f, 0.f, 0.f};

  const int lrow = lane >> 3;
  const int lcol = (lane & 7) * 8;

  for (int k0 = 0; k0 < K; k0 += 64) {
#pragma unroll
    for (int i = 0; i < 4; ++i) {
      int seg = i * 4 + wave;
      int row = seg * 8 + lrow;
      const ushort* gp = A + (size_t)(m0 + row) * K + k0 + lcol;
      ushort* lp = As + seg * 512;
      __builtin_amdgcn_global_load_lds((const __attribute__((address_space(1))) void*)gp,
                                       (__attribute__((address_space(3))) void*)lp, 16, 0, 0);
    }
#pragma unroll
    for (int i = 0; i < 4; ++i) {
      int seg = i * 4 + wave;
      int row = seg * 8 + lrow;
      const ushort* gp = Bt + (size_t)(n0 + row) * K + k0 + lcol;
      ushort* lp = Bs + seg * 512;
      __builtin_amdgcn_global_load_lds((const __attribute__((address_space(1))) void*)gp,
                                       (__attribute__((address_space(3))) void*)lp, 16, 0, 0);
    }
    __syncthreads();

#pragma unroll
    for (int kk = 0; kk < 64; kk += 32) {
      const int fr = lane & 15;
      const int fk = (lane >> 4) * 8 + kk;
      bf16x8 a[4], b[4];
#pragma unroll
      for (int mi = 0; mi < 4; ++mi)
        a[mi] = *(const bf16x8*)&As[(wm + mi * 16 + fr) * 64 + fk];
#pragma unroll
      for (int ni = 0; ni < 4; ++ni)
        b[ni] = *(const bf16x8*)&Bs[(wn + ni * 16 + fr) * 64 + fk];
#pragma unroll
      for (int mi = 0; mi < 4; ++mi)
#pragma unroll
        for (int ni = 0; ni < 4; ++ni)
          acc[mi][ni] = __builtin_amdgcn_mfma_f32_16x16x32_bf16(a[mi], b[ni], acc[mi][ni], 0, 0, 0);
    }
    __syncthreads();
  }

  const int cc = lane & 15;
  const int cr = (lane >> 4) * 4;
#pragma unroll
  for (int mi = 0; mi < 4; ++mi) {
#pragma unroll
    for (int ni = 0; ni < 4; ++ni) {
#pragma unroll
      for (int r = 0; r < 4; ++r) {
        int row = m0 + wm + mi * 16 + cr + r;
        int col = n0 + wn + ni * 16 + cc;
        size_t idx = (size_t)row * N + col;
        float v = acc[mi][ni][r];
        if (EPI == 0) {
          Cb[idx] = f2bf(v);
        } else {
          Cf[idx] = v + resid[idx];
        }
      }
    }
  }
}

// ---------------------------------------------------------------- sliding-window attention (MFMA band)
__global__ __launch_bounds__(256) void attn_win_mfma(const ushort* __restrict__ qkv,
                                                     ushort* __restrict__ msg) {
  __shared__ ushort Ks[80][72];
  __shared__ ushort Vt[64][88];
  __shared__ ushort Ps[4][16][40];

  const int tile = blockIdx.x;
  const int h = blockIdx.y;
  const int b = blockIdx.z;
  const int t0 = tile * 64;
  const size_t rowbase = (size_t)b * SEQ_T;
  const int tid = threadIdx.x;
  const int wave = tid >> 6;
  const int lane = tid & 63;

  for (int chunk = tid; chunk < 1280; chunk += 256) {
    int r = chunk >> 4;
    int c = (chunk & 15) * 8;
    int t = t0 - 16 + r;
    u16x8 u = {0, 0, 0, 0, 0, 0, 0, 0};
    if (t >= 0)
      u = *(const u16x8*)(qkv + (rowbase + t) * 3072 + 1024 + (size_t)h * 128 + c);
    if (c < 64) {
      *(u16x8*)&Ks[r][c] = u;
    } else {
      int d0 = c - 64;
#pragma unroll
      for (int j = 0; j < 8; ++j) Vt[d0 + j][r] = u[j];
    }
  }
  __syncthreads();

  const int fr = lane & 15;
  const int g = lane >> 4;
  const int rbase = wave * 16;

  bf16x8 qa[2];
#pragma unroll
  for (int kk = 0; kk < 2; ++kk)
    qa[kk] = *(const bf16x8*)(qkv + (rowbase + t0 + wave * 16 + fr) * 3072 +
                              (size_t)h * 64 + kk * 32 + g * 8);

  f32x4 sacc[2];
  sacc[0] = (f32x4){0.f, 0.f, 0.f, 0.f};
  sacc[1] = (f32x4){0.f, 0.f, 0.f, 0.f};
#pragma unroll
  for (int kk = 0; kk < 2; ++kk) {
#pragma unroll
    for (int nt = 0; nt < 2; ++nt) {
      bf16x8 kb = *(const bf16x8*)&Ks[rbase + nt * 16 + fr][kk * 32 + g * 8];
      sacc[nt] = __builtin_amdgcn_mfma_f32_16x16x32_bf16(qa[kk], kb, sacc[nt], 0, 0, 0);
    }
  }

#pragma unroll
  for (int nt = 0; nt < 2; ++nt) {
    int tk = t0 - 16 + rbase + nt * 16 + fr;
#pragma unroll
    for (int reg = 0; reg < 4; ++reg) {
      int t = t0 + wave * 16 + g * 4 + reg;
      float tau = 0.f;
      if (tk >= 0 && tk >= t - WIN && tk <= t - 1)
        tau = 1.f / (1.f + __expf(-sacc[nt][reg] * 0.125f));
      Ps[wave][g * 4 + reg][nt * 16 + fr] = f2bf(tau);
    }
  }
  __syncthreads();

  bf16x8 pa = *(const bf16x8*)&Ps[wave][fr][g * 8];
#pragma unroll
  for (int ct = 0; ct < 4; ++ct) {
    bf16x8 vb = *(const bf16x8*)&Vt[ct * 16 + fr][rbase + g * 8];
    f32x4 m = __builtin_amdgcn_mfma_f32_16x16x32_bf16(pa, vb, (f32x4){0.f, 0.f, 0.f, 0.f}, 0, 0, 0);
#pragma unroll
    for (int reg = 0; reg < 4; ++reg) {
      int t = t0 + wave * 16 + g * 4 + reg;
      msg[(rowbase + t) * 1024 + (size_t)h * 64 + ct * 16 + fr] = f2bf(m[reg]);
    }
  }
}

// ---------------------------------------------------------------- in-place LayerNorm (row=1024)
__global__ __launch_bounds__(256) void layernorm_inplace(float* __restrict__ y,
                                                         const float* __restrict__ gamma,
                                                         const float* __restrict__ beta) {
  const int row = blockIdx.x;
  float* p = y + (size_t)row * D_MODEL;
  const int tid = threadIdx.x;
  float4 v = *(const float4*)&p[tid * 4];
  float s = v.x + v.y + v.z + v.w;
  float s2 = v.x * v.x + v.y * v.y + v.z * v.z + v.w * v.w;
#pragma unroll
  for (int m = 1; m < 64; m <<= 1) {
    s += __shfl_xor(s, m);
    s2 += __shfl_xor(s2, m);
  }
  __shared__ float red[8];
  const int wave = tid >> 6, lane = tid & 63;
  if (lane == 0) { red[wave] = s; red[4 + wave] = s2; }
  __syncthreads();
  s = red[0] + red[1] + red[2] + red[3];
  s2 = red[4] + red[5] + red[6] + red[7];
  const float mu = s * (1.f / D_MODEL);
  const float var = s2 * (1.f / D_MODEL) - mu * mu;
  const float rstd = rsqrtf(var + 1e-5f);
  float4 g = *(const float4*)&gamma[tid * 4];
  float4 be = *(const float4*)&beta[tid * 4];
  float4 o;
  o.x = (v.x - mu) * rstd * g.x + be.x;
  o.y = (v.y - mu) * rstd * g.y + be.y;
  o.z = (v.z - mu) * rstd * g.z + be.z;
  o.w = (v.w - mu) * rstd * g.w + be.w;
  *(float4*)&p[tid * 4] = o;
}

// ---------------------------------------------------------------- launch
extern "C" void kernel_launch(void* const* d_in, const int* in_sizes, int n_in,
                              void* d_out, int out_size, void* d_ws, size_t ws_size,
                              hipStream_t stream) {
  (void)in_sizes; (void)n_in; (void)out_size; (void)ws_size;
  const float* x = (const float*)d_in[0];
  const float* wq = (const float*)d_in[1];
  const float* wkv = (const float*)d_in[2];
  const float* wo = (const float*)d_in[3];
  const float* gamma = (const float*)d_in[4];
  const float* beta = (const float*)d_in[5];
  float* out = (float*)d_out;

  ushort* xb = (ushort*)d_ws;                          // 8192x1024
  ushort* wb = xb + (size_t)8192 * 1024;               // 4096x1024: [wq;wkv;wo]
  ushort* qkvb = wb + (size_t)4096 * 1024;             // 8192x3072
  ushort* msgb = qkvb + (size_t)8192 * 3072;           // 8192x1024

  const int M = NBATCH * SEQ_T;  // 8192

  (void)hipFuncSetAttribute(reinterpret_cast<const void*>(&gemm1_8ph),
                            hipFuncAttributeMaxDynamicSharedMemorySize, 131072);

  cast_f32_bf16<<<(M * D_MODEL / 4 + 255) / 256, 256, 0, stream>>>((const float4*)x, xb, M * D_MODEL / 4);
  cast_f32_bf16<<<1024, 256, 0, stream>>>((const float4*)wq, wb, 262144);
  cast_f32_bf16<<<2048, 256, 0, stream>>>((const float4*)wkv, wb + (size_t)1024 * 1024, 524288);
  cast_f32_bf16<<<1024, 256, 0, stream>>>((const float4*)wo, wb + (size_t)3072 * 1024, 262144);

  // GEMM1: qkv = x @ [wq;wkv]^T   (M=8192, N=3072, K=1024), bf16 out, 8-phase 256^2
  gemm1_8ph<<<dim3(3072 / 256, M / 256), 512, 131072, stream>>>(xb, wb, qkvb, M, 3072, 1024);

  // windowed sigmoid attention -> msg (bf16), MFMA band formulation
  attn_win_mfma<<<dim3(SEQ_T / 64, NHEADS, NBATCH), 256, 0, stream>>>(qkvb, msgb);

  // GEMM2: y = x + msg @ wo^T  -> d_out (fp32)
  gemm_bt<1><<<dim3(1024 / 128, M / 128), 256, 0, stream>>>(msgb, wb + (size_t)3072 * 1024,
                                                            nullptr, out, x, M, 1024, 1024);
  // LayerNorm in place on d_out
  layernorm_inplace<<<M, 256, 0, stream>>>(out, gamma, beta);
}

// Round 4
// 140.448 us; speedup vs baseline: 2.1746x; 1.0214x over previous
//
#include <hip/hip_runtime.h>
#include <hip/hip_bf16.h>

// Problem constants (B=2, T=4096, D=1024, H=16, HD=64, W=16)
#define D_MODEL 1024
#define SEQ_T   4096
#define NBATCH  2
#define NHEADS  16
#define HEAD_D  64
#define WIN     16

typedef __attribute__((ext_vector_type(8))) short bf16x8;           // MFMA A/B frag
typedef __attribute__((ext_vector_type(8))) unsigned short u16x8;   // 16B bf16 load
typedef __attribute__((ext_vector_type(4))) float f32x4;            // MFMA C/D frag

__device__ __forceinline__ unsigned short f2bf(float f) {
  union { float f; unsigned int u; } v; v.f = f;
  unsigned int r = v.u + 0x7fffu + ((v.u >> 16) & 1u);  // RNE
  return (unsigned short)(r >> 16);
}
__device__ __forceinline__ float bf2f(unsigned short u) {
  union { unsigned int u; float f; } v; v.u = ((unsigned int)u) << 16;
  return v.f;
}

// ---------------------------------------------------------------- casts
__global__ __launch_bounds__(256) void cast_f32_bf16(const float4* __restrict__ src,
                                                     ushort* __restrict__ dst, int n4) {
  int i = blockIdx.x * 256 + threadIdx.x;
  if (i >= n4) return;
  float4 v = src[i];
  ushort4 o;
  o.x = f2bf(v.x); o.y = f2bf(v.y); o.z = f2bf(v.z); o.w = f2bf(v.w);
  *(ushort4*)(dst + (size_t)i * 4) = o;
}

// merged weight cast: dst = [wq 1M][wkv 2M][wo 1M] bf16; i indexes float4 units (1M total)
__global__ __launch_bounds__(256) void cast_weights(const float4* __restrict__ wq,
                                                    const float4* __restrict__ wkv,
                                                    const float4* __restrict__ wo,
                                                    ushort* __restrict__ dst) {
  int i = blockIdx.x * 256 + threadIdx.x;  // 0..1048575
  const float4* src;
  int off;
  if (i < 262144) { src = wq; off = 0; }
  else if (i < 786432) { src = wkv; off = 262144; }
  else { src = wo; off = 786432; }
  float4 v = src[i - off];
  ushort4 o;
  o.x = f2bf(v.x); o.y = f2bf(v.y); o.z = f2bf(v.z); o.w = f2bf(v.w);
  *(ushort4*)(dst + (size_t)i * 4) = o;
}

// ---------------------------------------------------------------- 2-phase 256x128 GEMM (T2+T3+T4+T5)
// C[m,n] = sum_k A[m,k]*Bt[n,k]; A MxK, Bt NxK row-major bf16.
// 512 thr = 8 waves (2M x 4N): wave rows {wr*64..+63} u {128+wr*64..+63}, cols wc*32..+31.
// 2 phases per K-tile: P0 = half0 (mq=0) reads A-half0(8)+B(4), P1 = half1 reads A-half1(8).
// LDS 96KiB: A[2dbuf][2half][128][64] @0, B[2dbuf][128][64] @64KiB. Chunk-XOR swizzle both-sides.
// Staging: P0 stages A1(t+1); P1 stages A0(t+2)+B(t+2); vmcnt(6) at end of every phase
// (in-order retirement: P0-end 8->6 retires A1(t); P1-end 10->6 retires A0B(t+1)).
// EPI=0: bf16 store. EPI=1: fp32 store + residual add.
#define SBAR() __builtin_amdgcn_s_barrier()
#define FENCE() __builtin_amdgcn_sched_barrier(0)
#define LGKM0() asm volatile("s_waitcnt lgkmcnt(0)" ::: "memory")
#define VMC6() asm volatile("s_waitcnt vmcnt(6)" ::: "memory")

template <int EPI>
__global__ __launch_bounds__(512, 2) void gemm_2ph(const ushort* __restrict__ A,
                                                   const ushort* __restrict__ Bt,
                                                   ushort* __restrict__ Cb,
                                                   float* __restrict__ Cf,
                                                   const float* __restrict__ resid,
                                                   int M, int N, int K) {
  extern __shared__ char smem[];  // 98304 bytes
  const int NTK = K >> 6;
  const int tid = threadIdx.x;
  const int wid = tid >> 6;
  const int lane = tid & 63;
  const int m0 = blockIdx.y * 256;
  const int n0 = blockIdx.x * 128;

  // staging lane geometry (pre-swizzled source chunk; involution c ^= row&7)
  const int l8 = lane >> 3;                    // row within 8-row segment
  const int lchunk = (lane & 7) ^ (l8 & 7);    // logical 16B chunk to fetch
  const ushort* pA = A + (size_t)(m0 + wid * 16 + l8) * K + lchunk * 8;
  const ushort* pB = Bt + (size_t)(n0 + wid * 16 + l8) * K + lchunk * 8;

#define STAGE_A(h, kt, db)                                                                 \
  {                                                                                        \
    _Pragma("unroll") for (int j = 0; j < 2; ++j) {                                        \
      const ushort* gp = pA + (size_t)((h) * 128 + j * 8) * K + (size_t)(kt) * 64;         \
      char* lp = smem + (db) * 32768 + (h) * 16384 + (wid * 2 + j) * 1024;                 \
      __builtin_amdgcn_global_load_lds((const __attribute__((address_space(1))) void*)gp,  \
                                       (__attribute__((address_space(3))) void*)lp, 16, 0, 0); \
    }                                                                                      \
  }
#define STAGE_B(kt, db)                                                                    \
  {                                                                                        \
    _Pragma("unroll") for (int j = 0; j < 2; ++j) {                                        \
      const ushort* gp = pB + (size_t)(j * 8) * K + (size_t)(kt) * 64;                     \
      char* lp = smem + 65536 + (db) * 16384 + (wid * 2 + j) * 1024;                       \
      __builtin_amdgcn_global_load_lds((const __attribute__((address_space(1))) void*)gp,  \
                                       (__attribute__((address_space(3))) void*)lp, 16, 0, 0); \
    }                                                                                      \
  }

  // compute-side lane geometry
  const int fr = lane & 15;
  const int g = lane >> 4;
  const int wr = wid >> 2;   // 0..1
  const int wc = wid & 3;    // 0..3
  int aRow[4], bRow[2], ch[2];
#pragma unroll
  for (int mi = 0; mi < 4; ++mi) aRow[mi] = (wr * 64 + mi * 16 + fr) * 128;
#pragma unroll
  for (int ni = 0; ni < 2; ++ni) bRow[ni] = (wc * 32 + ni * 16 + fr) * 128;
#pragma unroll
  for (int kk = 0; kk < 2; ++kk) ch[kk] = ((kk * 4 + g) ^ (fr & 7)) * 16;

  f32x4 acc[2][4][2];
#pragma unroll
  for (int mq = 0; mq < 2; ++mq)
#pragma unroll
    for (int mi = 0; mi < 4; ++mi)
#pragma unroll
      for (int ni = 0; ni < 2; ++ni) acc[mq][mi][ni] = (f32x4){0.f, 0.f, 0.f, 0.f};

  bf16x8 a[4][2], bf[2][2];

  // ---- prologue: tile0 {A0,B,A1} + tile1 {A0,B} = 10 loads; vmcnt(6) -> A0,B(0) arrived
  STAGE_A(0, 0, 0); STAGE_B(0, 0); STAGE_A(1, 0, 0);
  STAGE_A(0, 1, 1); STAGE_B(1, 1);
  VMC6();
  FENCE(); SBAR();

// kk-outer: 8 independent MFMAs between dependent acc pairs
#define PHASE_MFMA(mq)                                                         \
  __builtin_amdgcn_s_setprio(1);                                               \
  _Pragma("unroll") for (int kk = 0; kk < 2; ++kk)                             \
    _Pragma("unroll") for (int mi = 0; mi < 4; ++mi)                           \
      _Pragma("unroll") for (int ni = 0; ni < 2; ++ni)                         \
        acc[mq][mi][ni] = __builtin_amdgcn_mfma_f32_16x16x32_bf16(             \
            a[mi][kk], bf[ni][kk], acc[mq][mi][ni], 0, 0, 0);                  \
  __builtin_amdgcn_s_setprio(0);

#pragma unroll 1
  for (int t = 0; t < NTK; ++t) {
    const int db = t & 1;
    const int u1 = (t + 1 < NTK) ? t + 1 : NTK - 1;
    const int u2 = (t + 2 < NTK) ? t + 2 : NTK - 1;
    const int d1 = u1 & 1, d2 = u2 & 1;
    const char* Ab = smem + db * 32768;
    const char* Bb = smem + 65536 + db * 16384;

    // ---- P0 (mq=0): read A-half0 (8) + B (4); stage A1(u1); vmcnt retires A1(t)
#pragma unroll
    for (int mi = 0; mi < 4; ++mi)
#pragma unroll
      for (int kk = 0; kk < 2; ++kk)
        a[mi][kk] = *(const bf16x8*)(Ab + 0 * 16384 + aRow[mi] + ch[kk]);
#pragma unroll
    for (int ni = 0; ni < 2; ++ni)
#pragma unroll
      for (int kk = 0; kk < 2; ++kk)
        bf[ni][kk] = *(const bf16x8*)(Bb + bRow[ni] + ch[kk]);
    STAGE_A(1, u1, d1);
    FENCE(); SBAR(); LGKM0(); FENCE();
    PHASE_MFMA(0);
    FENCE(); VMC6(); SBAR();

    // ---- P1 (mq=1): read A-half1 (8); stage A0(u2)+B(u2); vmcnt retires A0B(t+1)
#pragma unroll
    for (int mi = 0; mi < 4; ++mi)
#pragma unroll
      for (int kk = 0; kk < 2; ++kk)
        a[mi][kk] = *(const bf16x8*)(Ab + 1 * 16384 + aRow[mi] + ch[kk]);
    STAGE_A(0, u2, d2);
    STAGE_B(u2, d2);
    FENCE(); SBAR(); LGKM0(); FENCE();
    PHASE_MFMA(1);
    FENCE(); VMC6(); SBAR();
  }

  // ---- epilogue: C/D layout col=lane&15, row=(lane>>4)*4+r
  const int cc = lane & 15;
  const int cr4 = (lane >> 4) * 4;
#pragma unroll
  for (int mq = 0; mq < 2; ++mq)
#pragma unroll
    for (int mi = 0; mi < 4; ++mi)
#pragma unroll
      for (int ni = 0; ni < 2; ++ni)
#pragma unroll
        for (int r = 0; r < 4; ++r) {
          int row = m0 + mq * 128 + wr * 64 + mi * 16 + cr4 + r;
          int col = n0 + wc * 32 + ni * 16 + cc;
          size_t idx = (size_t)row * N + col;
          float v = acc[mq][mi][ni][r];
          if (EPI == 0) {
            Cb[idx] = f2bf(v);
          } else {
            Cf[idx] = v + resid[idx];
          }
        }
#undef STAGE_A
#undef STAGE_B
#undef PHASE_MFMA
}

// ---------------------------------------------------------------- sliding-window attention (MFMA band)
__global__ __launch_bounds__(256) void attn_win_mfma(const ushort* __restrict__ qkv,
                                                     ushort* __restrict__ msg) {
  __shared__ ushort Ks[80][72];
  __shared__ ushort Vt[64][88];
  __shared__ ushort Ps[4][16][40];

  const int tile = blockIdx.x;
  const int h = blockIdx.y;
  const int b = blockIdx.z;
  const int t0 = tile * 64;
  const size_t rowbase = (size_t)b * SEQ_T;
  const int tid = threadIdx.x;
  const int wave = tid >> 6;
  const int lane = tid & 63;

  for (int chunk = tid; chunk < 1280; chunk += 256) {
    int r = chunk >> 4;
    int c = (chunk & 15) * 8;
    int t = t0 - 16 + r;
    u16x8 u = {0, 0, 0, 0, 0, 0, 0, 0};
    if (t >= 0)
      u = *(const u16x8*)(qkv + (rowbase + t) * 3072 + 1024 + (size_t)h * 128 + c);
    if (c < 64) {
      *(u16x8*)&Ks[r][c] = u;
    } else {
      int d0 = c - 64;
#pragma unroll
      for (int j = 0; j < 8; ++j) Vt[d0 + j][r] = u[j];
    }
  }
  __syncthreads();

  const int fr = lane & 15;
  const int g = lane >> 4;
  const int rbase = wave * 16;

  bf16x8 qa[2];
#pragma unroll
  for (int kk = 0; kk < 2; ++kk)
    qa[kk] = *(const bf16x8*)(qkv + (rowbase + t0 + wave * 16 + fr) * 3072 +
                              (size_t)h * 64 + kk * 32 + g * 8);

  f32x4 sacc[2];
  sacc[0] = (f32x4){0.f, 0.f, 0.f, 0.f};
  sacc[1] = (f32x4){0.f, 0.f, 0.f, 0.f};
#pragma unroll
  for (int kk = 0; kk < 2; ++kk) {
#pragma unroll
    for (int nt = 0; nt < 2; ++nt) {
      bf16x8 kb = *(const bf16x8*)&Ks[rbase + nt * 16 + fr][kk * 32 + g * 8];
      sacc[nt] = __builtin_amdgcn_mfma_f32_16x16x32_bf16(qa[kk], kb, sacc[nt], 0, 0, 0);
    }
  }

#pragma unroll
  for (int nt = 0; nt < 2; ++nt) {
    int tk = t0 - 16 + rbase + nt * 16 + fr;
#pragma unroll
    for (int reg = 0; reg < 4; ++reg) {
      int t = t0 + wave * 16 + g * 4 + reg;
      float tau = 0.f;
      if (tk >= 0 && tk >= t - WIN && tk <= t - 1)
        tau = 1.f / (1.f + __expf(-sacc[nt][reg] * 0.125f));
      Ps[wave][g * 4 + reg][nt * 16 + fr] = f2bf(tau);
    }
  }
  __syncthreads();

  bf16x8 pa = *(const bf16x8*)&Ps[wave][fr][g * 8];
#pragma unroll
  for (int ct = 0; ct < 4; ++ct) {
    bf16x8 vb = *(const bf16x8*)&Vt[ct * 16 + fr][rbase + g * 8];
    f32x4 m = __builtin_amdgcn_mfma_f32_16x16x32_bf16(pa, vb, (f32x4){0.f, 0.f, 0.f, 0.f}, 0, 0, 0);
#pragma unroll
    for (int reg = 0; reg < 4; ++reg) {
      int t = t0 + wave * 16 + g * 4 + reg;
      msg[(rowbase + t) * 1024 + (size_t)h * 64 + ct * 16 + fr] = f2bf(m[reg]);
    }
  }
}

// ---------------------------------------------------------------- in-place LayerNorm (row=1024)
__global__ __launch_bounds__(256) void layernorm_inplace(float* __restrict__ y,
                                                         const float* __restrict__ gamma,
                                                         const float* __restrict__ beta) {
  const int row = blockIdx.x;
  float* p = y + (size_t)row * D_MODEL;
  const int tid = threadIdx.x;
  float4 v = *(const float4*)&p[tid * 4];
  float s = v.x + v.y + v.z + v.w;
  float s2 = v.x * v.x + v.y * v.y + v.z * v.z + v.w * v.w;
#pragma unroll
  for (int m = 1; m < 64; m <<= 1) {
    s += __shfl_xor(s, m);
    s2 += __shfl_xor(s2, m);
  }
  __shared__ float red[8];
  const int wave = tid >> 6, lane = tid & 63;
  if (lane == 0) { red[wave] = s; red[4 + wave] = s2; }
  __syncthreads();
  s = red[0] + red[1] + red[2] + red[3];
  s2 = red[4] + red[5] + red[6] + red[7];
  const float mu = s * (1.f / D_MODEL);
  const float var = s2 * (1.f / D_MODEL) - mu * mu;
  const float rstd = rsqrtf(var + 1e-5f);
  float4 g = *(const float4*)&gamma[tid * 4];
  float4 be = *(const float4*)&beta[tid * 4];
  float4 o;
  o.x = (v.x - mu) * rstd * g.x + be.x;
  o.y = (v.y - mu) * rstd * g.y + be.y;
  o.z = (v.z - mu) * rstd * g.z + be.z;
  o.w = (v.w - mu) * rstd * g.w + be.w;
  *(float4*)&p[tid * 4] = o;
}

// ---------------------------------------------------------------- launch
extern "C" void kernel_launch(void* const* d_in, const int* in_sizes, int n_in,
                              void* d_out, int out_size, void* d_ws, size_t ws_size,
                              hipStream_t stream) {
  (void)in_sizes; (void)n_in; (void)out_size; (void)ws_size;
  const float* x = (const float*)d_in[0];
  const float* wq = (const float*)d_in[1];
  const float* wkv = (const float*)d_in[2];
  const float* wo = (const float*)d_in[3];
  const float* gamma = (const float*)d_in[4];
  const float* beta = (const float*)d_in[5];
  float* out = (float*)d_out;

  ushort* xb = (ushort*)d_ws;                          // 8192x1024
  ushort* wb = xb + (size_t)8192 * 1024;               // 4096x1024: [wq;wkv;wo]
  ushort* qkvb = wb + (size_t)4096 * 1024;             // 8192x3072
  ushort* msgb = qkvb + (size_t)8192 * 3072;           // 8192x1024

  const int M = NBATCH * SEQ_T;  // 8192

  (void)hipFuncSetAttribute(reinterpret_cast<const void*>(&gemm_2ph<0>),
                            hipFuncAttributeMaxDynamicSharedMemorySize, 98304);
  (void)hipFuncSetAttribute(reinterpret_cast<const void*>(&gemm_2ph<1>),
                            hipFuncAttributeMaxDynamicSharedMemorySize, 98304);

  cast_f32_bf16<<<(M * D_MODEL / 4 + 255) / 256, 256, 0, stream>>>((const float4*)x, xb, M * D_MODEL / 4);
  cast_weights<<<4096, 256, 0, stream>>>((const float4*)wq, (const float4*)wkv,
                                         (const float4*)wo, wb);

  // GEMM1: qkv = x @ [wq;wkv]^T  (M=8192, N=3072, K=1024) -> 24x32 = 768 blocks = 3 rounds
  gemm_2ph<0><<<dim3(3072 / 128, M / 256), 512, 98304, stream>>>(xb, wb, qkvb, nullptr, nullptr,
                                                                 M, 3072, 1024);

  // windowed sigmoid attention -> msg (bf16), MFMA band formulation
  attn_win_mfma<<<dim3(SEQ_T / 64, NHEADS, NBATCH), 256, 0, stream>>>(qkvb, msgb);

  // GEMM2: y = x + msg @ wo^T  (M=8192, N=1024, K=1024) -> 8x32 = 256 blocks = 1 round
  gemm_2ph<1><<<dim3(1024 / 128, M / 256), 512, 98304, stream>>>(msgb, wb + (size_t)3072 * 1024,
                                                                 nullptr, out, x, M, 1024, 1024);

  // LayerNorm in place on d_out
  layernorm_inplace<<<M, 256, 0, stream>>>(out, gamma, beta);
}

// Round 5
// 135.548 us; speedup vs baseline: 2.2532x; 1.0361x over previous
//
#include <hip/hip_runtime.h>
#include <hip/hip_bf16.h>

// Problem constants (B=2, T=4096, D=1024, H=16, HD=64, W=16)
#define D_MODEL 1024
#define SEQ_T   4096
#define NBATCH  2
#define NHEADS  16
#define HEAD_D  64
#define WIN     16

typedef __attribute__((ext_vector_type(8))) short bf16x8;           // MFMA A/B frag
typedef __attribute__((ext_vector_type(8))) unsigned short u16x8;   // 16B bf16 load
typedef __attribute__((ext_vector_type(4))) float f32x4;            // MFMA C/D frag

__device__ __forceinline__ unsigned short f2bf(float f) {
  union { float f; unsigned int u; } v; v.f = f;
  unsigned int r = v.u + 0x7fffu + ((v.u >> 16) & 1u);  // RNE
  return (unsigned short)(r >> 16);
}
__device__ __forceinline__ float bf2f(unsigned short u) {
  union { unsigned int u; float f; } v; v.u = ((unsigned int)u) << 16;
  return v.f;
}

// ---------------------------------------------------------------- casts
__global__ __launch_bounds__(256) void cast_f32_bf16(const float4* __restrict__ src,
                                                     ushort* __restrict__ dst, int n4) {
  int i = blockIdx.x * 256 + threadIdx.x;
  if (i >= n4) return;
  float4 v = src[i];
  ushort4 o;
  o.x = f2bf(v.x); o.y = f2bf(v.y); o.z = f2bf(v.z); o.w = f2bf(v.w);
  *(ushort4*)(dst + (size_t)i * 4) = o;
}

// merged weight cast: dst = [wq 1M][wkv 2M][wo 1M] bf16; i indexes float4 units (1M total)
__global__ __launch_bounds__(256) void cast_weights(const float4* __restrict__ wq,
                                                    const float4* __restrict__ wkv,
                                                    const float4* __restrict__ wo,
                                                    ushort* __restrict__ dst) {
  int i = blockIdx.x * 256 + threadIdx.x;  // 0..1048575
  const float4* src;
  int off;
  if (i < 262144) { src = wq; off = 0; }
  else if (i < 786432) { src = wkv; off = 262144; }
  else { src = wo; off = 786432; }
  float4 v = src[i - off];
  ushort4 o;
  o.x = f2bf(v.x); o.y = f2bf(v.y); o.z = f2bf(v.z); o.w = f2bf(v.w);
  *(ushort4*)(dst + (size_t)i * 4) = o;
}

// ---------------------------------------------------------------- 256x128 GEMM, 8 waves 4Mx2N
// C[m,n] = sum_k A[m,k]*Bt[n,k]; A MxK, Bt NxK row-major bf16.
// Per-wave 64x64 output (A-frags read ONCE per K-step, held across both phases).
// LDS 96KiB: A[2dbuf][256][64] @0 (32KB each), B[2dbuf][128][64] @64KiB (16KB each).
// Chunk-XOR swizzle both-sides (involution c ^= row&7). 2 phases/K-step, 2 barriers total:
//   P0: read A(8)+B-lo(4); STAGE_B(t+1); lgkm0; 16 MFMA acc[0]; vmcnt(2); s_barrier
//   P1: read B-hi(4);      STAGE_A(t+2); lgkm0; 16 MFMA acc[1]; vmcnt(4); s_barrier
// Per-wave FIFO ledger (4 A-loads + 2 B-loads per wave per K-step):
//   vmcnt(2) at P0-end retires A(t+1) [staged P1(t-1)], leaves B(t+1).
//   vmcnt(4) at P1-end retires B(t+1) [staged P0(t)], leaves A(t+2).
// lgkmcnt(0) before each exit barrier drains this wave's ds_reads -> exit barrier
// certifies all waves' reads done -> later stages into same region are safe.
// EPI=0: bf16 store. EPI=1: fp32 store + residual add.
#define SBAR() __builtin_amdgcn_s_barrier()
#define LGKM0() asm volatile("s_waitcnt lgkmcnt(0)" ::: "memory")
#define VMC(n) asm volatile("s_waitcnt vmcnt(" #n ")" ::: "memory")

template <int EPI>
__global__ __launch_bounds__(512, 2) void gemm_8w(const ushort* __restrict__ A,
                                                  const ushort* __restrict__ Bt,
                                                  ushort* __restrict__ Cb,
                                                  float* __restrict__ Cf,
                                                  const float* __restrict__ resid,
                                                  int M, int N, int K) {
  extern __shared__ char smem[];  // 98304 bytes
  const int NTK = K >> 6;
  const int tid = threadIdx.x;
  const int wid = tid >> 6;
  const int lane = tid & 63;
  const int m0 = blockIdx.y * 256;
  const int n0 = blockIdx.x * 128;

  // staging lane geometry (pre-swizzled source chunk; involution c ^= row&7)
  const int l8 = lane >> 3;                    // row within 8-row segment
  const int lchunk = (lane & 7) ^ (l8 & 7);    // logical 16B chunk to fetch
  const ushort* pA = A + (size_t)(m0 + wid * 8 + l8) * K + lchunk * 8;
  const ushort* pB = Bt + (size_t)(n0 + wid * 8 + l8) * K + lchunk * 8;

// A tile 256x64: 32 segs of 8 rows; seg = j*8+wid, j=0..3. Linear LDS dest (m104).
#define STAGE_A(kt, db)                                                                    \
  {                                                                                        \
    _Pragma("unroll") for (int j = 0; j < 4; ++j) {                                        \
      const ushort* gp = pA + (size_t)(j * 64) * K + (size_t)(kt) * 64;                    \
      char* lp = smem + (db) * 32768 + (j * 8 + wid) * 1024;                               \
      __builtin_amdgcn_global_load_lds((const __attribute__((address_space(1))) void*)gp,  \
                                       (__attribute__((address_space(3))) void*)lp, 16, 0, 0); \
    }                                                                                      \
  }
// B tile 128x64: 16 segs; seg = j*8+wid, j=0..1.
#define STAGE_B(kt, db)                                                                    \
  {                                                                                        \
    _Pragma("unroll") for (int j = 0; j < 2; ++j) {                                        \
      const ushort* gp = pB + (size_t)(j * 64) * K + (size_t)(kt) * 64;                    \
      char* lp = smem + 65536 + (db) * 16384 + (j * 8 + wid) * 1024;                       \
      __builtin_amdgcn_global_load_lds((const __attribute__((address_space(1))) void*)gp,  \
                                       (__attribute__((address_space(3))) void*)lp, 16, 0, 0); \
    }                                                                                      \
  }

  // compute-side lane geometry
  const int fr = lane & 15;
  const int g = lane >> 4;
  const int wr = wid >> 1;   // 0..3  (64-row band)
  const int wc = wid & 1;    // 0..1  (64-col band)
  int aRow[4], bRow[2][2], ch[2];
#pragma unroll
  for (int mi = 0; mi < 4; ++mi) aRow[mi] = (wr * 64 + mi * 16 + fr) * 128;
#pragma unroll
  for (int nq = 0; nq < 2; ++nq)
#pragma unroll
    for (int ni = 0; ni < 2; ++ni) bRow[nq][ni] = (wc * 64 + nq * 32 + ni * 16 + fr) * 128;
#pragma unroll
  for (int kk = 0; kk < 2; ++kk) ch[kk] = ((kk * 4 + g) ^ (fr & 7)) * 16;

  f32x4 acc[2][4][2];
#pragma unroll
  for (int nq = 0; nq < 2; ++nq)
#pragma unroll
    for (int mi = 0; mi < 4; ++mi)
#pragma unroll
      for (int ni = 0; ni < 2; ++ni) acc[nq][mi][ni] = (f32x4){0.f, 0.f, 0.f, 0.f};

  bf16x8 a[4][2], b0[2][2], b1[2][2];

  // ---- prologue: A(0) B(0) A(1) = 10 loads; vmcnt(4) -> A(0),B(0) arrived
  STAGE_A(0, 0); STAGE_B(0, 0); STAGE_A(1, 1);
  VMC(4);
  SBAR();

#define PHASE_MFMA(nq, bfr)                                                    \
  __builtin_amdgcn_s_setprio(1);                                               \
  _Pragma("unroll") for (int kk = 0; kk < 2; ++kk)                             \
    _Pragma("unroll") for (int mi = 0; mi < 4; ++mi)                           \
      _Pragma("unroll") for (int ni = 0; ni < 2; ++ni)                         \
        acc[nq][mi][ni] = __builtin_amdgcn_mfma_f32_16x16x32_bf16(             \
            a[mi][kk], bfr[ni][kk], acc[nq][mi][ni], 0, 0, 0);                 \
  __builtin_amdgcn_s_setprio(0);

#pragma unroll 1
  for (int t = 0; t < NTK; ++t) {
    const int db = t & 1;
    const int u1 = (t + 1 < NTK) ? t + 1 : NTK - 1;
    const int u2 = (t + 2 < NTK) ? t + 2 : NTK - 1;
    const int d1 = u1 & 1, d2 = u2 & 1;
    const char* Ab = smem + db * 32768;
    const char* Bb = smem + 65536 + db * 16384;

    // ---- P0: read A (8) + B-lo (4); stage B(t+1)
#pragma unroll
    for (int mi = 0; mi < 4; ++mi)
#pragma unroll
      for (int kk = 0; kk < 2; ++kk)
        a[mi][kk] = *(const bf16x8*)(Ab + aRow[mi] + ch[kk]);
#pragma unroll
    for (int ni = 0; ni < 2; ++ni)
#pragma unroll
      for (int kk = 0; kk < 2; ++kk)
        b0[ni][kk] = *(const bf16x8*)(Bb + bRow[0][ni] + ch[kk]);
    STAGE_B(u1, d1);
    LGKM0();
    PHASE_MFMA(0, b0);
    VMC(2);
    SBAR();

    // ---- P1: read B-hi (4); stage A(t+2)
#pragma unroll
    for (int ni = 0; ni < 2; ++ni)
#pragma unroll
      for (int kk = 0; kk < 2; ++kk)
        b1[ni][kk] = *(const bf16x8*)(Bb + bRow[1][ni] + ch[kk]);
    STAGE_A(u2, d2);
    LGKM0();
    PHASE_MFMA(1, b1);
    VMC(4);
    SBAR();
  }

  // ---- epilogue: C/D layout col=lane&15, row=(lane>>4)*4+r
  const int cc = lane & 15;
  const int cr4 = (lane >> 4) * 4;
#pragma unroll
  for (int nq = 0; nq < 2; ++nq)
#pragma unroll
    for (int mi = 0; mi < 4; ++mi)
#pragma unroll
      for (int ni = 0; ni < 2; ++ni)
#pragma unroll
        for (int r = 0; r < 4; ++r) {
          int row = m0 + wr * 64 + mi * 16 + cr4 + r;
          int col = n0 + wc * 64 + nq * 32 + ni * 16 + cc;
          size_t idx = (size_t)row * N + col;
          float v = acc[nq][mi][ni][r];
          if (EPI == 0) {
            Cb[idx] = f2bf(v);
          } else {
            Cf[idx] = v + resid[idx];
          }
        }
#undef STAGE_A
#undef STAGE_B
#undef PHASE_MFMA
}

// ---------------------------------------------------------------- sliding-window attention (MFMA band)
__global__ __launch_bounds__(256) void attn_win_mfma(const ushort* __restrict__ qkv,
                                                     ushort* __restrict__ msg) {
  __shared__ ushort Ks[80][72];
  __shared__ ushort Vt[64][88];
  __shared__ ushort Ps[4][16][40];

  const int tile = blockIdx.x;
  const int h = blockIdx.y;
  const int b = blockIdx.z;
  const int t0 = tile * 64;
  const size_t rowbase = (size_t)b * SEQ_T;
  const int tid = threadIdx.x;
  const int wave = tid >> 6;
  const int lane = tid & 63;

  for (int chunk = tid; chunk < 1280; chunk += 256) {
    int r = chunk >> 4;
    int c = (chunk & 15) * 8;
    int t = t0 - 16 + r;
    u16x8 u = {0, 0, 0, 0, 0, 0, 0, 0};
    if (t >= 0)
      u = *(const u16x8*)(qkv + (rowbase + t) * 3072 + 1024 + (size_t)h * 128 + c);
    if (c < 64) {
      *(u16x8*)&Ks[r][c] = u;
    } else {
      int d0 = c - 64;
#pragma unroll
      for (int j = 0; j < 8; ++j) Vt[d0 + j][r] = u[j];
    }
  }
  __syncthreads();

  const int fr = lane & 15;
  const int g = lane >> 4;
  const int rbase = wave * 16;

  bf16x8 qa[2];
#pragma unroll
  for (int kk = 0; kk < 2; ++kk)
    qa[kk] = *(const bf16x8*)(qkv + (rowbase + t0 + wave * 16 + fr) * 3072 +
                              (size_t)h * 64 + kk * 32 + g * 8);

  f32x4 sacc[2];
  sacc[0] = (f32x4){0.f, 0.f, 0.f, 0.f};
  sacc[1] = (f32x4){0.f, 0.f, 0.f, 0.f};
#pragma unroll
  for (int kk = 0; kk < 2; ++kk) {
#pragma unroll
    for (int nt = 0; nt < 2; ++nt) {
      bf16x8 kb = *(const bf16x8*)&Ks[rbase + nt * 16 + fr][kk * 32 + g * 8];
      sacc[nt] = __builtin_amdgcn_mfma_f32_16x16x32_bf16(qa[kk], kb, sacc[nt], 0, 0, 0);
    }
  }

#pragma unroll
  for (int nt = 0; nt < 2; ++nt) {
    int tk = t0 - 16 + rbase + nt * 16 + fr;
#pragma unroll
    for (int reg = 0; reg < 4; ++reg) {
      int t = t0 + wave * 16 + g * 4 + reg;
      float tau = 0.f;
      if (tk >= 0 && tk >= t - WIN && tk <= t - 1)
        tau = 1.f / (1.f + __expf(-sacc[nt][reg] * 0.125f));
      Ps[wave][g * 4 + reg][nt * 16 + fr] = f2bf(tau);
    }
  }
  __syncthreads();

  bf16x8 pa = *(const bf16x8*)&Ps[wave][fr][g * 8];
#pragma unroll
  for (int ct = 0; ct < 4; ++ct) {
    bf16x8 vb = *(const bf16x8*)&Vt[ct * 16 + fr][rbase + g * 8];
    f32x4 m = __builtin_amdgcn_mfma_f32_16x16x32_bf16(pa, vb, (f32x4){0.f, 0.f, 0.f, 0.f}, 0, 0, 0);
#pragma unroll
    for (int reg = 0; reg < 4; ++reg) {
      int t = t0 + wave * 16 + g * 4 + reg;
      msg[(rowbase + t) * 1024 + (size_t)h * 64 + ct * 16 + fr] = f2bf(m[reg]);
    }
  }
}

// ---------------------------------------------------------------- in-place LayerNorm (row=1024)
__global__ __launch_bounds__(256) void layernorm_inplace(float* __restrict__ y,
                                                         const float* __restrict__ gamma,
                                                         const float* __restrict__ beta) {
  const int row = blockIdx.x;
  float* p = y + (size_t)row * D_MODEL;
  const int tid = threadIdx.x;
  float4 v = *(const float4*)&p[tid * 4];
  float s = v.x + v.y + v.z + v.w;
  float s2 = v.x * v.x + v.y * v.y + v.z * v.z + v.w * v.w;
#pragma unroll
  for (int m = 1; m < 64; m <<= 1) {
    s += __shfl_xor(s, m);
    s2 += __shfl_xor(s2, m);
  }
  __shared__ float red[8];
  const int wave = tid >> 6, lane = tid & 63;
  if (lane == 0) { red[wave] = s; red[4 + wave] = s2; }
  __syncthreads();
  s = red[0] + red[1] + red[2] + red[3];
  s2 = red[4] + red[5] + red[6] + red[7];
  const float mu = s * (1.f / D_MODEL);
  const float var = s2 * (1.f / D_MODEL) - mu * mu;
  const float rstd = rsqrtf(var + 1e-5f);
  float4 g = *(const float4*)&gamma[tid * 4];
  float4 be = *(const float4*)&beta[tid * 4];
  float4 o;
  o.x = (v.x - mu) * rstd * g.x + be.x;
  o.y = (v.y - mu) * rstd * g.y + be.y;
  o.z = (v.z - mu) * rstd * g.z + be.z;
  o.w = (v.w - mu) * rstd * g.w + be.w;
  *(float4*)&p[tid * 4] = o;
}

// ---------------------------------------------------------------- launch
extern "C" void kernel_launch(void* const* d_in, const int* in_sizes, int n_in,
                              void* d_out, int out_size, void* d_ws, size_t ws_size,
                              hipStream_t stream) {
  (void)in_sizes; (void)n_in; (void)out_size; (void)ws_size;
  const float* x = (const float*)d_in[0];
  const float* wq = (const float*)d_in[1];
  const float* wkv = (const float*)d_in[2];
  const float* wo = (const float*)d_in[3];
  const float* gamma = (const float*)d_in[4];
  const float* beta = (const float*)d_in[5];
  float* out = (float*)d_out;

  ushort* xb = (ushort*)d_ws;                          // 8192x1024
  ushort* wb = xb + (size_t)8192 * 1024;               // 4096x1024: [wq;wkv;wo]
  ushort* qkvb = wb + (size_t)4096 * 1024;             // 8192x3072
  ushort* msgb = qkvb + (size_t)8192 * 3072;           // 8192x1024

  const int M = NBATCH * SEQ_T;  // 8192

  (void)hipFuncSetAttribute(reinterpret_cast<const void*>(&gemm_8w<0>),
                            hipFuncAttributeMaxDynamicSharedMemorySize, 98304);
  (void)hipFuncSetAttribute(reinterpret_cast<const void*>(&gemm_8w<1>),
                            hipFuncAttributeMaxDynamicSharedMemorySize, 98304);

  cast_f32_bf16<<<(M * D_MODEL / 4 + 255) / 256, 256, 0, stream>>>((const float4*)x, xb, M * D_MODEL / 4);
  cast_weights<<<4096, 256, 0, stream>>>((const float4*)wq, (const float4*)wkv,
                                         (const float4*)wo, wb);

  // GEMM1: qkv = x @ [wq;wkv]^T  (M=8192, N=3072, K=1024) -> 24x32 = 768 blocks = 3 rounds
  gemm_8w<0><<<dim3(3072 / 128, M / 256), 512, 98304, stream>>>(xb, wb, qkvb, nullptr, nullptr,
                                                                M, 3072, 1024);

  // windowed sigmoid attention -> msg (bf16), MFMA band formulation
  attn_win_mfma<<<dim3(SEQ_T / 64, NHEADS, NBATCH), 256, 0, stream>>>(qkvb, msgb);

  // GEMM2: y = x + msg @ wo^T  (M=8192, N=1024, K=1024) -> 8x32 = 256 blocks = 1 round
  gemm_8w<1><<<dim3(1024 / 128, M / 256), 512, 98304, stream>>>(msgb, wb + (size_t)3072 * 1024,
                                                                nullptr, out, x, M, 1024, 1024);

  // LayerNorm in place on d_out
  layernorm_inplace<<<M, 256, 0, stream>>>(out, gamma, beta);
}

// Round 6
// 133.059 us; speedup vs baseline: 2.2954x; 1.0187x over previous
//
#include <hip/hip_runtime.h>
#include <hip/hip_bf16.h>

// Problem constants (B=2, T=4096, D=1024, H=16, HD=64, W=16)
#define D_MODEL 1024
#define SEQ_T   4096
#define NBATCH  2
#define NHEADS  16
#define HEAD_D  64
#define WIN     16

typedef __attribute__((ext_vector_type(8))) short bf16x8;           // MFMA A/B frag
typedef __attribute__((ext_vector_type(8))) unsigned short u16x8;   // 16B bf16 load
typedef __attribute__((ext_vector_type(4))) float f32x4;            // MFMA C/D frag

__device__ __forceinline__ unsigned short f2bf(float f) {
  union { float f; unsigned int u; } v; v.f = f;
  unsigned int r = v.u + 0x7fffu + ((v.u >> 16) & 1u);  // RNE
  return (unsigned short)(r >> 16);
}
__device__ __forceinline__ float bf2f(unsigned short u) {
  union { unsigned int u; float f; } v; v.u = ((unsigned int)u) << 16;
  return v.f;
}

#define SBAR() __builtin_amdgcn_s_barrier()
#define LGKM0() asm volatile("s_waitcnt lgkmcnt(0)" ::: "memory")
#define VMC(n) asm volatile("s_waitcnt vmcnt(" #n ")" ::: "memory")

// ---------------------------------------------------------------- casts
__global__ __launch_bounds__(256) void cast_f32_bf16(const float4* __restrict__ src,
                                                     ushort* __restrict__ dst, int n4) {
  int i = blockIdx.x * 256 + threadIdx.x;
  if (i >= n4) return;
  float4 v = src[i];
  ushort4 o;
  o.x = f2bf(v.x); o.y = f2bf(v.y); o.z = f2bf(v.z); o.w = f2bf(v.w);
  *(ushort4*)(dst + (size_t)i * 4) = o;
}

// merged weight cast: dst = [wq 1M][wkv 2M][wo 1M] bf16; i indexes float4 units (1M total)
__global__ __launch_bounds__(256) void cast_weights(const float4* __restrict__ wq,
                                                    const float4* __restrict__ wkv,
                                                    const float4* __restrict__ wo,
                                                    ushort* __restrict__ dst) {
  int i = blockIdx.x * 256 + threadIdx.x;  // 0..1048575
  const float4* src;
  int off;
  if (i < 262144) { src = wq; off = 0; }
  else if (i < 786432) { src = wkv; off = 262144; }
  else { src = wo; off = 786432; }
  float4 v = src[i - off];
  ushort4 o;
  o.x = f2bf(v.x); o.y = f2bf(v.y); o.z = f2bf(v.z); o.w = f2bf(v.w);
  *(ushort4*)(dst + (size_t)i * 4) = o;
}

// ---------------------------------------------------------------- GEMM1: 256x192, 4-phase
// C[m,n] = sum_k A[m,k]*Bt[n,k]; bf16 out. Grid 16x32 = 512 blocks = 2.0 rounds.
// 8 waves 4Mx2N: per-wave 64 rows x 96 cols (acc[4][6]). A-frags read once at P0, held.
// LDS 112KiB: A[2][256][64] @0 (32KB each), B[2][192][64] @64KiB (24KB each).
// Chunk-XOR swizzle both-sides (involution c ^= row&7).
// Phases (nh, kk): P0(0,0) reads A(8)+B(3), stages B(t+1); P1(0,1) reads B(3), stages A(t+2);
// P2(1,0) reads B(3); P3(1,1) reads B(3), vmcnt(4) before exit barrier.
// FIFO ledger (7 loads/wave/K-tile: 3B@P0 + 4A@P1): at P3, outstanding =
// A(t+1)[P1(t-1)] 4 + B(t+1)[P0(t)] 3 + A(t+2)[P1(t)] 4 = 11 -> vmcnt(4) retires
// A(t+1),B(t+1), leaves A(t+2). Prologue A0(4),B0(3),A1(4) -> vmcnt(4) matches.
// No sched_barrier (m141: order-pinning costs 1.7x; compiler tracks C++ ds_reads itself).
__global__ __launch_bounds__(512, 2) void gemm1_192(const ushort* __restrict__ A,
                                                    const ushort* __restrict__ Bt,
                                                    ushort* __restrict__ C,
                                                    int M, int N, int K) {
  extern __shared__ char smem[];  // 114688 bytes
  const int NTK = K >> 6;
  const int tid = threadIdx.x;
  const int wid = tid >> 6;
  const int lane = tid & 63;
  const int m0 = blockIdx.y * 256;
  const int n0 = blockIdx.x * 192;

  // staging lane geometry (pre-swizzled source chunk; involution c ^= row&7)
  const int l8 = lane >> 3;
  const int lchunk = (lane & 7) ^ (l8 & 7);
  const ushort* pA = A + (size_t)(m0 + wid * 8 + l8) * K + lchunk * 8;
  const ushort* pB = Bt + (size_t)(n0 + wid * 8 + l8) * K + lchunk * 8;

// A tile 256x64 = 32 segs of 8 rows; per-wave 4 (j*8+wid).
#define STAGE_A(kt, db)                                                                    \
  {                                                                                        \
    _Pragma("unroll") for (int j = 0; j < 4; ++j) {                                        \
      const ushort* gp = pA + (size_t)(j * 64) * K + (size_t)(kt) * 64;                    \
      char* lp = smem + (db) * 32768 + (j * 8 + wid) * 1024;                               \
      __builtin_amdgcn_global_load_lds((const __attribute__((address_space(1))) void*)gp,  \
                                       (__attribute__((address_space(3))) void*)lp, 16, 0, 0); \
    }                                                                                      \
  }
// B tile 192x64 = 24 segs; per-wave 3.
#define STAGE_B(kt, db)                                                                    \
  {                                                                                        \
    _Pragma("unroll") for (int j = 0; j < 3; ++j) {                                        \
      const ushort* gp = pB + (size_t)(j * 64) * K + (size_t)(kt) * 64;                    \
      char* lp = smem + 65536 + (db) * 24576 + (j * 8 + wid) * 1024;                       \
      __builtin_amdgcn_global_load_lds((const __attribute__((address_space(1))) void*)gp,  \
                                       (__attribute__((address_space(3))) void*)lp, 16, 0, 0); \
    }                                                                                      \
  }

  // compute-side lane geometry
  const int fr = lane & 15;
  const int g = lane >> 4;
  const int wr = wid >> 1;   // 0..3  (64-row band)
  const int wc = wid & 1;    // 0..1  (96-col band)
  int aRow[4], bRow[6], ch[2];
#pragma unroll
  for (int mi = 0; mi < 4; ++mi) aRow[mi] = (wr * 64 + mi * 16 + fr) * 128;
#pragma unroll
  for (int j = 0; j < 6; ++j) bRow[j] = (wc * 96 + j * 16 + fr) * 128;
#pragma unroll
  for (int kk = 0; kk < 2; ++kk) ch[kk] = ((kk * 4 + g) ^ (fr & 7)) * 16;

  f32x4 acc[4][6];
#pragma unroll
  for (int mi = 0; mi < 4; ++mi)
#pragma unroll
    for (int j = 0; j < 6; ++j) acc[mi][j] = (f32x4){0.f, 0.f, 0.f, 0.f};

  bf16x8 a[4][2], b[3];

  // ---- prologue: A(0) B(0) A(1) = 11 loads; vmcnt(4) -> A(0),B(0) arrived; barrier
  STAGE_A(0, 0); STAGE_B(0, 0); STAGE_A(1, 1);
  VMC(4);
  SBAR();

#pragma unroll 1
  for (int t = 0; t < NTK; ++t) {
    const int db = t & 1;
    const int u1 = (t + 1 < NTK) ? t + 1 : NTK - 1;
    const int u2 = (t + 2 < NTK) ? t + 2 : NTK - 1;
    const int d1 = u1 & 1, d2 = u2 & 1;
    const char* Ab = smem + db * 32768;
    const char* Bb = smem + 65536 + db * 24576;

    // ---- P0 (nh0,kk0): read all A (8) + B[0..2][kk0]; stage B(t+1)
#pragma unroll
    for (int mi = 0; mi < 4; ++mi)
#pragma unroll
      for (int kk = 0; kk < 2; ++kk)
        a[mi][kk] = *(const bf16x8*)(Ab + aRow[mi] + ch[kk]);
#pragma unroll
    for (int ni = 0; ni < 3; ++ni) b[ni] = *(const bf16x8*)(Bb + bRow[ni] + ch[0]);
    STAGE_B(u1, d1);
    SBAR();
    LGKM0();
    __builtin_amdgcn_s_setprio(1);
#pragma unroll
    for (int mi = 0; mi < 4; ++mi)
#pragma unroll
      for (int ni = 0; ni < 3; ++ni)
        acc[mi][ni] = __builtin_amdgcn_mfma_f32_16x16x32_bf16(a[mi][0], b[ni], acc[mi][ni], 0, 0, 0);
    __builtin_amdgcn_s_setprio(0);
    SBAR();

    // ---- P1 (nh0,kk1): read B[0..2][kk1]; stage A(t+2)
#pragma unroll
    for (int ni = 0; ni < 3; ++ni) b[ni] = *(const bf16x8*)(Bb + bRow[ni] + ch[1]);
    STAGE_A(u2, d2);
    SBAR();
    LGKM0();
    __builtin_amdgcn_s_setprio(1);
#pragma unroll
    for (int mi = 0; mi < 4; ++mi)
#pragma unroll
      for (int ni = 0; ni < 3; ++ni)
        acc[mi][ni] = __builtin_amdgcn_mfma_f32_16x16x32_bf16(a[mi][1], b[ni], acc[mi][ni], 0, 0, 0);
    __builtin_amdgcn_s_setprio(0);
    SBAR();

    // ---- P2 (nh1,kk0): read B[3..5][kk0]
#pragma unroll
    for (int ni = 0; ni < 3; ++ni) b[ni] = *(const bf16x8*)(Bb + bRow[3 + ni] + ch[0]);
    SBAR();
    LGKM0();
    __builtin_amdgcn_s_setprio(1);
#pragma unroll
    for (int mi = 0; mi < 4; ++mi)
#pragma unroll
      for (int ni = 0; ni < 3; ++ni)
        acc[mi][3 + ni] = __builtin_amdgcn_mfma_f32_16x16x32_bf16(a[mi][0], b[ni], acc[mi][3 + ni], 0, 0, 0);
    __builtin_amdgcn_s_setprio(0);
    SBAR();

    // ---- P3 (nh1,kk1): read B[3..5][kk1]; vmcnt(4) before exit barrier
#pragma unroll
    for (int ni = 0; ni < 3; ++ni) b[ni] = *(const bf16x8*)(Bb + bRow[3 + ni] + ch[1]);
    SBAR();
    LGKM0();
    __builtin_amdgcn_s_setprio(1);
#pragma unroll
    for (int mi = 0; mi < 4; ++mi)
#pragma unroll
      for (int ni = 0; ni < 3; ++ni)
        acc[mi][3 + ni] = __builtin_amdgcn_mfma_f32_16x16x32_bf16(a[mi][1], b[ni], acc[mi][3 + ni], 0, 0, 0);
    __builtin_amdgcn_s_setprio(0);
    VMC(4);
    SBAR();
  }

  // ---- epilogue: C/D layout col=lane&15, row=(lane>>4)*4+r
  const int cc = lane & 15;
  const int cr4 = (lane >> 4) * 4;
#pragma unroll
  for (int mi = 0; mi < 4; ++mi)
#pragma unroll
    for (int j = 0; j < 6; ++j)
#pragma unroll
      for (int r = 0; r < 4; ++r) {
        int row = m0 + wr * 64 + mi * 16 + cr4 + r;
        int col = n0 + wc * 96 + j * 16 + cc;
        C[(size_t)row * N + col] = f2bf(acc[mi][j][r]);
      }
#undef STAGE_A
#undef STAGE_B
}

// ---------------------------------------------------------------- GEMM2: 256x128, 8 waves 4Mx2N
// (R5 structure; 256 blocks = 1 round.) EPI=1: fp32 store + residual add.
template <int EPI>
__global__ __launch_bounds__(512, 2) void gemm_8w(const ushort* __restrict__ A,
                                                  const ushort* __restrict__ Bt,
                                                  ushort* __restrict__ Cb,
                                                  float* __restrict__ Cf,
                                                  const float* __restrict__ resid,
                                                  int M, int N, int K) {
  extern __shared__ char smem[];  // 98304 bytes
  const int NTK = K >> 6;
  const int tid = threadIdx.x;
  const int wid = tid >> 6;
  const int lane = tid & 63;
  const int m0 = blockIdx.y * 256;
  const int n0 = blockIdx.x * 128;

  const int l8 = lane >> 3;
  const int lchunk = (lane & 7) ^ (l8 & 7);
  const ushort* pA = A + (size_t)(m0 + wid * 8 + l8) * K + lchunk * 8;
  const ushort* pB = Bt + (size_t)(n0 + wid * 8 + l8) * K + lchunk * 8;

#define STAGE_A(kt, db)                                                                    \
  {                                                                                        \
    _Pragma("unroll") for (int j = 0; j < 4; ++j) {                                        \
      const ushort* gp = pA + (size_t)(j * 64) * K + (size_t)(kt) * 64;                    \
      char* lp = smem + (db) * 32768 + (j * 8 + wid) * 1024;                               \
      __builtin_amdgcn_global_load_lds((const __attribute__((address_space(1))) void*)gp,  \
                                       (__attribute__((address_space(3))) void*)lp, 16, 0, 0); \
    }                                                                                      \
  }
#define STAGE_B(kt, db)                                                                    \
  {                                                                                        \
    _Pragma("unroll") for (int j = 0; j < 2; ++j) {                                        \
      const ushort* gp = pB + (size_t)(j * 64) * K + (size_t)(kt) * 64;                    \
      char* lp = smem + 65536 + (db) * 16384 + (j * 8 + wid) * 1024;                       \
      __builtin_amdgcn_global_load_lds((const __attribute__((address_space(1))) void*)gp,  \
                                       (__attribute__((address_space(3))) void*)lp, 16, 0, 0); \
    }                                                                                      \
  }

  const int fr = lane & 15;
  const int g = lane >> 4;
  const int wr = wid >> 1;
  const int wc = wid & 1;
  int aRow[4], bRow[2][2], ch[2];
#pragma unroll
  for (int mi = 0; mi < 4; ++mi) aRow[mi] = (wr * 64 + mi * 16 + fr) * 128;
#pragma unroll
  for (int nq = 0; nq < 2; ++nq)
#pragma unroll
    for (int ni = 0; ni < 2; ++ni) bRow[nq][ni] = (wc * 64 + nq * 32 + ni * 16 + fr) * 128;
#pragma unroll
  for (int kk = 0; kk < 2; ++kk) ch[kk] = ((kk * 4 + g) ^ (fr & 7)) * 16;

  f32x4 acc[2][4][2];
#pragma unroll
  for (int nq = 0; nq < 2; ++nq)
#pragma unroll
    for (int mi = 0; mi < 4; ++mi)
#pragma unroll
      for (int ni = 0; ni < 2; ++ni) acc[nq][mi][ni] = (f32x4){0.f, 0.f, 0.f, 0.f};

  bf16x8 a[4][2], b0[2][2], b1[2][2];

  STAGE_A(0, 0); STAGE_B(0, 0); STAGE_A(1, 1);
  VMC(4);
  SBAR();

#define PHASE_MFMA(nq, bfr)                                                    \
  __builtin_amdgcn_s_setprio(1);                                               \
  _Pragma("unroll") for (int kk = 0; kk < 2; ++kk)                             \
    _Pragma("unroll") for (int mi = 0; mi < 4; ++mi)                           \
      _Pragma("unroll") for (int ni = 0; ni < 2; ++ni)                         \
        acc[nq][mi][ni] = __builtin_amdgcn_mfma_f32_16x16x32_bf16(             \
            a[mi][kk], bfr[ni][kk], acc[nq][mi][ni], 0, 0, 0);                 \
  __builtin_amdgcn_s_setprio(0);

#pragma unroll 1
  for (int t = 0; t < NTK; ++t) {
    const int db = t & 1;
    const int u1 = (t + 1 < NTK) ? t + 1 : NTK - 1;
    const int u2 = (t + 2 < NTK) ? t + 2 : NTK - 1;
    const int d1 = u1 & 1, d2 = u2 & 1;
    const char* Ab = smem + db * 32768;
    const char* Bb = smem + 65536 + db * 16384;

#pragma unroll
    for (int mi = 0; mi < 4; ++mi)
#pragma unroll
      for (int kk = 0; kk < 2; ++kk)
        a[mi][kk] = *(const bf16x8*)(Ab + aRow[mi] + ch[kk]);
#pragma unroll
    for (int ni = 0; ni < 2; ++ni)
#pragma unroll
      for (int kk = 0; kk < 2; ++kk)
        b0[ni][kk] = *(const bf16x8*)(Bb + bRow[0][ni] + ch[kk]);
    STAGE_B(u1, d1);
    LGKM0();
    PHASE_MFMA(0, b0);
    VMC(2);
    SBAR();

#pragma unroll
    for (int ni = 0; ni < 2; ++ni)
#pragma unroll
      for (int kk = 0; kk < 2; ++kk)
        b1[ni][kk] = *(const bf16x8*)(Bb + bRow[1][ni] + ch[kk]);
    STAGE_A(u2, d2);
    LGKM0();
    PHASE_MFMA(1, b1);
    VMC(4);
    SBAR();
  }

  const int cc = lane & 15;
  const int cr4 = (lane >> 4) * 4;
#pragma unroll
  for (int nq = 0; nq < 2; ++nq)
#pragma unroll
    for (int mi = 0; mi < 4; ++mi)
#pragma unroll
      for (int ni = 0; ni < 2; ++ni)
#pragma unroll
        for (int r = 0; r < 4; ++r) {
          int row = m0 + wr * 64 + mi * 16 + cr4 + r;
          int col = n0 + wc * 64 + nq * 32 + ni * 16 + cc;
          size_t idx = (size_t)row * N + col;
          float v = acc[nq][mi][ni][r];
          if (EPI == 0) {
            Cb[idx] = f2bf(v);
          } else {
            Cf[idx] = v + resid[idx];
          }
        }
#undef STAGE_A
#undef STAGE_B
#undef PHASE_MFMA
}

// ---------------------------------------------------------------- sliding-window attention (MFMA band)
__global__ __launch_bounds__(256) void attn_win_mfma(const ushort* __restrict__ qkv,
                                                     ushort* __restrict__ msg) {
  __shared__ ushort Ks[80][72];
  __shared__ ushort Vt[64][88];
  __shared__ ushort Ps[4][16][40];

  const int tile = blockIdx.x;
  const int h = blockIdx.y;
  const int b = blockIdx.z;
  const int t0 = tile * 64;
  const size_t rowbase = (size_t)b * SEQ_T;
  const int tid = threadIdx.x;
  const int wave = tid >> 6;
  const int lane = tid & 63;

  for (int chunk = tid; chunk < 1280; chunk += 256) {
    int r = chunk >> 4;
    int c = (chunk & 15) * 8;
    int t = t0 - 16 + r;
    u16x8 u = {0, 0, 0, 0, 0, 0, 0, 0};
    if (t >= 0)
      u = *(const u16x8*)(qkv + (rowbase + t) * 3072 + 1024 + (size_t)h * 128 + c);
    if (c < 64) {
      *(u16x8*)&Ks[r][c] = u;
    } else {
      int d0 = c - 64;
#pragma unroll
      for (int j = 0; j < 8; ++j) Vt[d0 + j][r] = u[j];
    }
  }
  __syncthreads();

  const int fr = lane & 15;
  const int g = lane >> 4;
  const int rbase = wave * 16;

  bf16x8 qa[2];
#pragma unroll
  for (int kk = 0; kk < 2; ++kk)
    qa[kk] = *(const bf16x8*)(qkv + (rowbase + t0 + wave * 16 + fr) * 3072 +
                              (size_t)h * 64 + kk * 32 + g * 8);

  f32x4 sacc[2];
  sacc[0] = (f32x4){0.f, 0.f, 0.f, 0.f};
  sacc[1] = (f32x4){0.f, 0.f, 0.f, 0.f};
#pragma unroll
  for (int kk = 0; kk < 2; ++kk) {
#pragma unroll
    for (int nt = 0; nt < 2; ++nt) {
      bf16x8 kb = *(const bf16x8*)&Ks[rbase + nt * 16 + fr][kk * 32 + g * 8];
      sacc[nt] = __builtin_amdgcn_mfma_f32_16x16x32_bf16(qa[kk], kb, sacc[nt], 0, 0, 0);
    }
  }

#pragma unroll
  for (int nt = 0; nt < 2; ++nt) {
    int tk = t0 - 16 + rbase + nt * 16 + fr;
#pragma unroll
    for (int reg = 0; reg < 4; ++reg) {
      int t = t0 + wave * 16 + g * 4 + reg;
      float tau = 0.f;
      if (tk >= 0 && tk >= t - WIN && tk <= t - 1)
        tau = 1.f / (1.f + __expf(-sacc[nt][reg] * 0.125f));
      Ps[wave][g * 4 + reg][nt * 16 + fr] = f2bf(tau);
    }
  }
  __syncthreads();

  bf16x8 pa = *(const bf16x8*)&Ps[wave][fr][g * 8];
#pragma unroll
  for (int ct = 0; ct < 4; ++ct) {
    bf16x8 vb = *(const bf16x8*)&Vt[ct * 16 + fr][rbase + g * 8];
    f32x4 m = __builtin_amdgcn_mfma_f32_16x16x32_bf16(pa, vb, (f32x4){0.f, 0.f, 0.f, 0.f}, 0, 0, 0);
#pragma unroll
    for (int reg = 0; reg < 4; ++reg) {
      int t = t0 + wave * 16 + g * 4 + reg;
      msg[(rowbase + t) * 1024 + (size_t)h * 64 + ct * 16 + fr] = f2bf(m[reg]);
    }
  }
}

// ---------------------------------------------------------------- in-place LayerNorm (row=1024)
__global__ __launch_bounds__(256) void layernorm_inplace(float* __restrict__ y,
                                                         const float* __restrict__ gamma,
                                                         const float* __restrict__ beta) {
  const int row = blockIdx.x;
  float* p = y + (size_t)row * D_MODEL;
  const int tid = threadIdx.x;
  float4 v = *(const float4*)&p[tid * 4];
  float s = v.x + v.y + v.z + v.w;
  float s2 = v.x * v.x + v.y * v.y + v.z * v.z + v.w * v.w;
#pragma unroll
  for (int m = 1; m < 64; m <<= 1) {
    s += __shfl_xor(s, m);
    s2 += __shfl_xor(s2, m);
  }
  __shared__ float red[8];
  const int wave = tid >> 6, lane = tid & 63;
  if (lane == 0) { red[wave] = s; red[4 + wave] = s2; }
  __syncthreads();
  s = red[0] + red[1] + red[2] + red[3];
  s2 = red[4] + red[5] + red[6] + red[7];
  const float mu = s * (1.f / D_MODEL);
  const float var = s2 * (1.f / D_MODEL) - mu * mu;
  const float rstd = rsqrtf(var + 1e-5f);
  float4 g = *(const float4*)&gamma[tid * 4];
  float4 be = *(const float4*)&beta[tid * 4];
  float4 o;
  o.x = (v.x - mu) * rstd * g.x + be.x;
  o.y = (v.y - mu) * rstd * g.y + be.y;
  o.z = (v.z - mu) * rstd * g.z + be.z;
  o.w = (v.w - mu) * rstd * g.w + be.w;
  *(float4*)&p[tid * 4] = o;
}

// ---------------------------------------------------------------- launch
extern "C" void kernel_launch(void* const* d_in, const int* in_sizes, int n_in,
                              void* d_out, int out_size, void* d_ws, size_t ws_size,
                              hipStream_t stream) {
  (void)in_sizes; (void)n_in; (void)out_size; (void)ws_size;
  const float* x = (const float*)d_in[0];
  const float* wq = (const float*)d_in[1];
  const float* wkv = (const float*)d_in[2];
  const float* wo = (const float*)d_in[3];
  const float* gamma = (const float*)d_in[4];
  const float* beta = (const float*)d_in[5];
  float* out = (float*)d_out;

  ushort* xb = (ushort*)d_ws;                          // 8192x1024
  ushort* wb = xb + (size_t)8192 * 1024;               // 4096x1024: [wq;wkv;wo]
  ushort* qkvb = wb + (size_t)4096 * 1024;             // 8192x3072
  ushort* msgb = qkvb + (size_t)8192 * 3072;           // 8192x1024

  const int M = NBATCH * SEQ_T;  // 8192

  (void)hipFuncSetAttribute(reinterpret_cast<const void*>(&gemm1_192),
                            hipFuncAttributeMaxDynamicSharedMemorySize, 114688);
  (void)hipFuncSetAttribute(reinterpret_cast<const void*>(&gemm_8w<1>),
                            hipFuncAttributeMaxDynamicSharedMemorySize, 98304);

  cast_f32_bf16<<<(M * D_MODEL / 4 + 255) / 256, 256, 0, stream>>>((const float4*)x, xb, M * D_MODEL / 4);
  cast_weights<<<4096, 256, 0, stream>>>((const float4*)wq, (const float4*)wkv,
                                         (const float4*)wo, wb);

  // GEMM1: qkv = x @ [wq;wkv]^T  (M=8192, N=3072, K=1024) -> 16x32 = 512 blocks = 2.0 rounds
  gemm1_192<<<dim3(3072 / 192, M / 256), 512, 114688, stream>>>(xb, wb, qkvb, M, 3072, 1024);

  // windowed sigmoid attention -> msg (bf16), MFMA band formulation
  attn_win_mfma<<<dim3(SEQ_T / 64, NHEADS, NBATCH), 256, 0, stream>>>(qkvb, msgb);

  // GEMM2: y = x + msg @ wo^T  (M=8192, N=1024, K=1024) -> 8x32 = 256 blocks = 1 round
  gemm_8w<1><<<dim3(1024 / 128, M / 256), 512, 98304, stream>>>(msgb, wb + (size_t)3072 * 1024,
                                                                nullptr, out, x, M, 1024, 1024);

  // LayerNorm in place on d_out
  layernorm_inplace<<<M, 256, 0, stream>>>(out, gamma, beta);
}

// Round 7
// 131.468 us; speedup vs baseline: 2.3232x; 1.0121x over previous
//
#include <hip/hip_runtime.h>
#include <hip/hip_bf16.h>

// Problem constants (B=2, T=4096, D=1024, H=16, HD=64, W=16)
#define D_MODEL 1024
#define SEQ_T   4096
#define NBATCH  2
#define NHEADS  16
#define HEAD_D  64
#define WIN     16

typedef __attribute__((ext_vector_type(8))) short bf16x8;           // MFMA A/B frag
typedef __attribute__((ext_vector_type(8))) unsigned short u16x8;   // 16B bf16 load
typedef __attribute__((ext_vector_type(4))) float f32x4;            // MFMA C/D frag

__device__ __forceinline__ unsigned short f2bf(float f) {
  union { float f; unsigned int u; } v; v.f = f;
  unsigned int r = v.u + 0x7fffu + ((v.u >> 16) & 1u);  // RNE
  return (unsigned short)(r >> 16);
}
__device__ __forceinline__ float bf2f(unsigned short u) {
  union { unsigned int u; float f; } v; v.u = ((unsigned int)u) << 16;
  return v.f;
}

#define SBAR() __builtin_amdgcn_s_barrier()
#define LGKM0() asm volatile("s_waitcnt lgkmcnt(0)" ::: "memory")
#define LGKM8() asm volatile("s_waitcnt lgkmcnt(8)" ::: "memory")
#define VMC(n) asm volatile("s_waitcnt vmcnt(" #n ")" ::: "memory")

// ---------------------------------------------------------------- casts
__global__ __launch_bounds__(256) void cast_f32_bf16(const float4* __restrict__ src,
                                                     ushort* __restrict__ dst, int n4) {
  int i = blockIdx.x * 256 + threadIdx.x;
  if (i >= n4) return;
  float4 v = src[i];
  ushort4 o;
  o.x = f2bf(v.x); o.y = f2bf(v.y); o.z = f2bf(v.z); o.w = f2bf(v.w);
  *(ushort4*)(dst + (size_t)i * 4) = o;
}

// merged weight cast: dst = [wq 1M][wkv 2M][wo 1M] bf16; i indexes float4 units (1M total)
__global__ __launch_bounds__(256) void cast_weights(const float4* __restrict__ wq,
                                                    const float4* __restrict__ wkv,
                                                    const float4* __restrict__ wo,
                                                    ushort* __restrict__ dst) {
  int i = blockIdx.x * 256 + threadIdx.x;  // 0..1048575
  const float4* src;
  int off;
  if (i < 262144) { src = wq; off = 0; }
  else if (i < 786432) { src = wkv; off = 262144; }
  else { src = wo; off = 786432; }
  float4 v = src[i - off];
  ushort4 o;
  o.x = f2bf(v.x); o.y = f2bf(v.y); o.z = f2bf(v.z); o.w = f2bf(v.w);
  *(ushort4*)(dst + (size_t)i * 4) = o;
}

// ---------------------------------------------------------------- GEMM1: 256x192, 6-phase/2-K-tile
// m201-faithful schedule at BN=192. 8 waves 4Mx2N (per-wave 64x96, acc[4][6]).
// LDS 112KiB: A[2][256][64] @0 (32KB/buf), B[2][192][64] @64KiB (24KB/buf).
// Per K-tile 3 phases of 16 MFMA (nh col-thirds); A-frags read once at nh0, held.
// Staging: ONE unit per phase, placed after the unit's region's last reader:
//   p1: B(2i+1)->db1   (db1-B last read prev iter p6)
//   p2: A01(2i+2)->db0 (db0-A last read p1)
//   p3: A23(2i+2)->db0; vmcnt(4)  [retires A(2i+1),B(2i+1); leaves A(2i+2)]
//   p4: B(2i+2)->db0   (db0-B last read p3)
//   p5: A01(2i+3)->db1 (db1-A last read p4)
//   p6: A23(2i+3)->db1; vmcnt(4)  [retires B(2i+2),A(2i+2); leaves A(2i+3)]
// Loads/thread: A-unit=2, B-unit=3; prologue A(0)4+B(0)3+A(1)4=11, vmcnt(4).
// Phase = {ds_reads; 1 stage unit; [lgkm8 if 12 reads]; [vmcnt]; SBAR; lgkm0; setprio+16 MFMA; SBAR}.
// No sched_barrier anywhere (m141). Tail clamps restage identical bytes (benign).
__global__ __launch_bounds__(512, 2) void gemm1_6ph(const ushort* __restrict__ A,
                                                    const ushort* __restrict__ Bt,
                                                    ushort* __restrict__ C,
                                                    int M, int N, int K) {
  extern __shared__ char smem[];  // 114688 bytes
  const int tid = threadIdx.x;
  const int wid = tid >> 6;
  const int lane = tid & 63;
  const int m0 = blockIdx.y * 256;
  const int n0 = blockIdx.x * 192;

  // staging lane geometry (pre-swizzled source chunk; involution c ^= row&7)
  const int l8 = lane >> 3;
  const int lchunk = (lane & 7) ^ (l8 & 7);
  const ushort* pA = A + (size_t)(m0 + wid * 8 + l8) * K + lchunk * 8;
  const ushort* pB = Bt + (size_t)(n0 + wid * 8 + l8) * K + lchunk * 8;

// stage A rows [j0*64, (j0+2)*64) of k-tile kt into buffer db (2 loads/thread)
#define SA(kt, db, j0)                                                                     \
  {                                                                                        \
    _Pragma("unroll") for (int j = (j0); j < (j0) + 2; ++j) {                              \
      const ushort* gp = pA + (size_t)(j * 64) * K + (size_t)(kt) * 64;                    \
      char* lp = smem + (db) * 32768 + (j * 8 + wid) * 1024;                               \
      __builtin_amdgcn_global_load_lds((const __attribute__((address_space(1))) void*)gp,  \
                                       (__attribute__((address_space(3))) void*)lp, 16, 0, 0); \
    }                                                                                      \
  }
// stage full B tile (192 rows) of k-tile kt into buffer db (3 loads/thread)
#define SB(kt, db)                                                                         \
  {                                                                                        \
    _Pragma("unroll") for (int j = 0; j < 3; ++j) {                                        \
      const ushort* gp = pB + (size_t)(j * 64) * K + (size_t)(kt) * 64;                    \
      char* lp = smem + 65536 + (db) * 24576 + (j * 8 + wid) * 1024;                       \
      __builtin_amdgcn_global_load_lds((const __attribute__((address_space(1))) void*)gp,  \
                                       (__attribute__((address_space(3))) void*)lp, 16, 0, 0); \
    }                                                                                      \
  }

  // compute-side lane geometry
  const int fr = lane & 15;
  const int g = lane >> 4;
  const int wr = wid >> 1;   // 0..3  (64-row band)
  const int wc = wid & 1;    // 0..1  (96-col band)
  int aRow[4], bRow[6], ch[2];
#pragma unroll
  for (int mi = 0; mi < 4; ++mi) aRow[mi] = (wr * 64 + mi * 16 + fr) * 128;
#pragma unroll
  for (int j = 0; j < 6; ++j) bRow[j] = (wc * 96 + j * 16 + fr) * 128;
#pragma unroll
  for (int kk = 0; kk < 2; ++kk) ch[kk] = ((kk * 4 + g) ^ (fr & 7)) * 16;

  f32x4 acc[4][6];
#pragma unroll
  for (int mi = 0; mi < 4; ++mi)
#pragma unroll
    for (int j = 0; j < 6; ++j) acc[mi][j] = (f32x4){0.f, 0.f, 0.f, 0.f};

  bf16x8 a[4][2], b[2][2];

#define RD_A(db)                                                               \
  _Pragma("unroll") for (int mi = 0; mi < 4; ++mi)                             \
    _Pragma("unroll") for (int kk = 0; kk < 2; ++kk)                           \
      a[mi][kk] = *(const bf16x8*)(smem + (db) * 32768 + aRow[mi] + ch[kk]);
#define RD_B(db, nh)                                                           \
  _Pragma("unroll") for (int ni = 0; ni < 2; ++ni)                             \
    _Pragma("unroll") for (int kk = 0; kk < 2; ++kk)                           \
      b[ni][kk] = *(const bf16x8*)(smem + 65536 + (db) * 24576 +               \
                                   bRow[(nh) * 2 + ni] + ch[kk]);
#define MM(nh)                                                                 \
  __builtin_amdgcn_s_setprio(1);                                               \
  _Pragma("unroll") for (int kk = 0; kk < 2; ++kk)                             \
    _Pragma("unroll") for (int mi = 0; mi < 4; ++mi)                           \
      _Pragma("unroll") for (int ni = 0; ni < 2; ++ni)                         \
        acc[mi][(nh) * 2 + ni] = __builtin_amdgcn_mfma_f32_16x16x32_bf16(      \
            a[mi][kk], b[ni][kk], acc[mi][(nh) * 2 + ni], 0, 0, 0);            \
  __builtin_amdgcn_s_setprio(0);

  // ---- prologue: A(0),B(0),A(1) = 11 loads; vmcnt(4) -> tile0 arrived, A(1) in flight
  SA(0, 0, 0); SA(0, 0, 2); SB(0, 0); SA(1, 1, 0); SA(1, 1, 2);
  VMC(4);
  SBAR();

#pragma unroll 1
  for (int i = 0; i < 8; ++i) {
    const int t1 = 2 * i + 1;                       // <= 15, no clamp
    const int t2 = (2 * i + 2 < 16) ? 2 * i + 2 : 15;
    const int t3 = (2 * i + 3 < 16) ? 2 * i + 3 : 15;
    const int d2 = t2 & 1, d3 = t3 & 1;

    // ---- p1: tile 2i (db0) nh0; stage B(t1)->db1
    RD_A(0); RD_B(0, 0);
    SB(t1, 1);
    LGKM8();
    SBAR(); LGKM0();
    MM(0);
    SBAR();

    // ---- p2: nh1; stage A01(t2)
    RD_B(0, 1);
    SA(t2, d2, 0);
    SBAR(); LGKM0();
    MM(1);
    SBAR();

    // ---- p3: nh2; stage A23(t2); vmcnt(4) -> tile t1 fully arrived
    RD_B(0, 2);
    SA(t2, d2, 2);
    VMC(4);
    SBAR(); LGKM0();
    MM(2);
    SBAR();

    // ---- p4: tile 2i+1 (db1) nh0; stage B(t2)
    RD_A(1); RD_B(1, 0);
    SB(t2, d2);
    LGKM8();
    SBAR(); LGKM0();
    MM(0);
    SBAR();

    // ---- p5: nh1; stage A01(t3)
    RD_B(1, 1);
    SA(t3, d3, 0);
    SBAR(); LGKM0();
    MM(1);
    SBAR();

    // ---- p6: nh2; stage A23(t3); vmcnt(4) -> tile t2 fully arrived
    RD_B(1, 2);
    SA(t3, d3, 2);
    VMC(4);
    SBAR(); LGKM0();
    MM(2);
    SBAR();
  }

  // ---- epilogue: C/D layout col=lane&15, row=(lane>>4)*4+r
  const int cc = lane & 15;
  const int cr4 = (lane >> 4) * 4;
#pragma unroll
  for (int mi = 0; mi < 4; ++mi)
#pragma unroll
    for (int j = 0; j < 6; ++j)
#pragma unroll
      for (int r = 0; r < 4; ++r) {
        int row = m0 + wr * 64 + mi * 16 + cr4 + r;
        int col = n0 + wc * 96 + j * 16 + cc;
        C[(size_t)row * N + col] = f2bf(acc[mi][j][r]);
      }
#undef SA
#undef SB
#undef RD_A
#undef RD_B
#undef MM
}

// ---------------------------------------------------------------- GEMM2: 256x128, 8 waves 4Mx2N
// (R5 structure; 256 blocks = 1 round.) EPI=1: fp32 store + residual add.
template <int EPI>
__global__ __launch_bounds__(512, 2) void gemm_8w(const ushort* __restrict__ A,
                                                  const ushort* __restrict__ Bt,
                                                  ushort* __restrict__ Cb,
                                                  float* __restrict__ Cf,
                                                  const float* __restrict__ resid,
                                                  int M, int N, int K) {
  extern __shared__ char smem[];  // 98304 bytes
  const int NTK = K >> 6;
  const int tid = threadIdx.x;
  const int wid = tid >> 6;
  const int lane = tid & 63;
  const int m0 = blockIdx.y * 256;
  const int n0 = blockIdx.x * 128;

  const int l8 = lane >> 3;
  const int lchunk = (lane & 7) ^ (l8 & 7);
  const ushort* pA = A + (size_t)(m0 + wid * 8 + l8) * K + lchunk * 8;
  const ushort* pB = Bt + (size_t)(n0 + wid * 8 + l8) * K + lchunk * 8;

#define STAGE_A(kt, db)                                                                    \
  {                                                                                        \
    _Pragma("unroll") for (int j = 0; j < 4; ++j) {                                        \
      const ushort* gp = pA + (size_t)(j * 64) * K + (size_t)(kt) * 64;                    \
      char* lp = smem + (db) * 32768 + (j * 8 + wid) * 1024;                               \
      __builtin_amdgcn_global_load_lds((const __attribute__((address_space(1))) void*)gp,  \
                                       (__attribute__((address_space(3))) void*)lp, 16, 0, 0); \
    }                                                                                      \
  }
#define STAGE_B(kt, db)                                                                    \
  {                                                                                        \
    _Pragma("unroll") for (int j = 0; j < 2; ++j) {                                        \
      const ushort* gp = pB + (size_t)(j * 64) * K + (size_t)(kt) * 64;                    \
      char* lp = smem + 65536 + (db) * 16384 + (j * 8 + wid) * 1024;                       \
      __builtin_amdgcn_global_load_lds((const __attribute__((address_space(1))) void*)gp,  \
                                       (__attribute__((address_space(3))) void*)lp, 16, 0, 0); \
    }                                                                                      \
  }

  const int fr = lane & 15;
  const int g = lane >> 4;
  const int wr = wid >> 1;
  const int wc = wid & 1;
  int aRow[4], bRow[2][2], ch[2];
#pragma unroll
  for (int mi = 0; mi < 4; ++mi) aRow[mi] = (wr * 64 + mi * 16 + fr) * 128;
#pragma unroll
  for (int nq = 0; nq < 2; ++nq)
#pragma unroll
    for (int ni = 0; ni < 2; ++ni) bRow[nq][ni] = (wc * 64 + nq * 32 + ni * 16 + fr) * 128;
#pragma unroll
  for (int kk = 0; kk < 2; ++kk) ch[kk] = ((kk * 4 + g) ^ (fr & 7)) * 16;

  f32x4 acc[2][4][2];
#pragma unroll
  for (int nq = 0; nq < 2; ++nq)
#pragma unroll
    for (int mi = 0; mi < 4; ++mi)
#pragma unroll
      for (int ni = 0; ni < 2; ++ni) acc[nq][mi][ni] = (f32x4){0.f, 0.f, 0.f, 0.f};

  bf16x8 a[4][2], b0[2][2], b1[2][2];

  STAGE_A(0, 0); STAGE_B(0, 0); STAGE_A(1, 1);
  VMC(4);
  SBAR();

#define PHASE_MFMA(nq, bfr)                                                    \
  __builtin_amdgcn_s_setprio(1);                                               \
  _Pragma("unroll") for (int kk = 0; kk < 2; ++kk)                             \
    _Pragma("unroll") for (int mi = 0; mi < 4; ++mi)                           \
      _Pragma("unroll") for (int ni = 0; ni < 2; ++ni)                         \
        acc[nq][mi][ni] = __builtin_amdgcn_mfma_f32_16x16x32_bf16(             \
            a[mi][kk], bfr[ni][kk], acc[nq][mi][ni], 0, 0, 0);                 \
  __builtin_amdgcn_s_setprio(0);

#pragma unroll 1
  for (int t = 0; t < NTK; ++t) {
    const int db = t & 1;
    const int u1 = (t + 1 < NTK) ? t + 1 : NTK - 1;
    const int u2 = (t + 2 < NTK) ? t + 2 : NTK - 1;
    const int d1 = u1 & 1, d2 = u2 & 1;
    const char* Ab = smem + db * 32768;
    const char* Bb = smem + 65536 + db * 16384;

#pragma unroll
    for (int mi = 0; mi < 4; ++mi)
#pragma unroll
      for (int kk = 0; kk < 2; ++kk)
        a[mi][kk] = *(const bf16x8*)(Ab + aRow[mi] + ch[kk]);
#pragma unroll
    for (int ni = 0; ni < 2; ++ni)
#pragma unroll
      for (int kk = 0; kk < 2; ++kk)
        b0[ni][kk] = *(const bf16x8*)(Bb + bRow[0][ni] + ch[kk]);
    STAGE_B(u1, d1);
    LGKM0();
    PHASE_MFMA(0, b0);
    VMC(2);
    SBAR();

#pragma unroll
    for (int ni = 0; ni < 2; ++ni)
#pragma unroll
      for (int kk = 0; kk < 2; ++kk)
        b1[ni][kk] = *(const bf16x8*)(Bb + bRow[1][ni] + ch[kk]);
    STAGE_A(u2, d2);
    LGKM0();
    PHASE_MFMA(1, b1);
    VMC(4);
    SBAR();
  }

  const int cc = lane & 15;
  const int cr4 = (lane >> 4) * 4;
#pragma unroll
  for (int nq = 0; nq < 2; ++nq)
#pragma unroll
    for (int mi = 0; mi < 4; ++mi)
#pragma unroll
      for (int ni = 0; ni < 2; ++ni)
#pragma unroll
        for (int r = 0; r < 4; ++r) {
          int row = m0 + wr * 64 + mi * 16 + cr4 + r;
          int col = n0 + wc * 64 + nq * 32 + ni * 16 + cc;
          size_t idx = (size_t)row * N + col;
          float v = acc[nq][mi][ni][r];
          if (EPI == 0) {
            Cb[idx] = f2bf(v);
          } else {
            Cf[idx] = v + resid[idx];
          }
        }
#undef STAGE_A
#undef STAGE_B
#undef PHASE_MFMA
}

// ---------------------------------------------------------------- sliding-window attention (MFMA band)
__global__ __launch_bounds__(256) void attn_win_mfma(const ushort* __restrict__ qkv,
                                                     ushort* __restrict__ msg) {
  __shared__ ushort Ks[80][72];
  __shared__ ushort Vt[64][88];
  __shared__ ushort Ps[4][16][40];

  const int tile = blockIdx.x;
  const int h = blockIdx.y;
  const int b = blockIdx.z;
  const int t0 = tile * 64;
  const size_t rowbase = (size_t)b * SEQ_T;
  const int tid = threadIdx.x;
  const int wave = tid >> 6;
  const int lane = tid & 63;

  for (int chunk = tid; chunk < 1280; chunk += 256) {
    int r = chunk >> 4;
    int c = (chunk & 15) * 8;
    int t = t0 - 16 + r;
    u16x8 u = {0, 0, 0, 0, 0, 0, 0, 0};
    if (t >= 0)
      u = *(const u16x8*)(qkv + (rowbase + t) * 3072 + 1024 + (size_t)h * 128 + c);
    if (c < 64) {
      *(u16x8*)&Ks[r][c] = u;
    } else {
      int d0 = c - 64;
#pragma unroll
      for (int j = 0; j < 8; ++j) Vt[d0 + j][r] = u[j];
    }
  }
  __syncthreads();

  const int fr = lane & 15;
  const int g = lane >> 4;
  const int rbase = wave * 16;

  bf16x8 qa[2];
#pragma unroll
  for (int kk = 0; kk < 2; ++kk)
    qa[kk] = *(const bf16x8*)(qkv + (rowbase + t0 + wave * 16 + fr) * 3072 +
                              (size_t)h * 64 + kk * 32 + g * 8);

  f32x4 sacc[2];
  sacc[0] = (f32x4){0.f, 0.f, 0.f, 0.f};
  sacc[1] = (f32x4){0.f, 0.f, 0.f, 0.f};
#pragma unroll
  for (int kk = 0; kk < 2; ++kk) {
#pragma unroll
    for (int nt = 0; nt < 2; ++nt) {
      bf16x8 kb = *(const bf16x8*)&Ks[rbase + nt * 16 + fr][kk * 32 + g * 8];
      sacc[nt] = __builtin_amdgcn_mfma_f32_16x16x32_bf16(qa[kk], kb, sacc[nt], 0, 0, 0);
    }
  }

#pragma unroll
  for (int nt = 0; nt < 2; ++nt) {
    int tk = t0 - 16 + rbase + nt * 16 + fr;
#pragma unroll
    for (int reg = 0; reg < 4; ++reg) {
      int t = t0 + wave * 16 + g * 4 + reg;
      float tau = 0.f;
      if (tk >= 0 && tk >= t - WIN && tk <= t - 1)
        tau = 1.f / (1.f + __expf(-sacc[nt][reg] * 0.125f));
      Ps[wave][g * 4 + reg][nt * 16 + fr] = f2bf(tau);
    }
  }
  __syncthreads();

  bf16x8 pa = *(const bf16x8*)&Ps[wave][fr][g * 8];
#pragma unroll
  for (int ct = 0; ct < 4; ++ct) {
    bf16x8 vb = *(const bf16x8*)&Vt[ct * 16 + fr][rbase + g * 8];
    f32x4 m = __builtin_amdgcn_mfma_f32_16x16x32_bf16(pa, vb, (f32x4){0.f, 0.f, 0.f, 0.f}, 0, 0, 0);
#pragma unroll
    for (int reg = 0; reg < 4; ++reg) {
      int t = t0 + wave * 16 + g * 4 + reg;
      msg[(rowbase + t) * 1024 + (size_t)h * 64 + ct * 16 + fr] = f2bf(m[reg]);
    }
  }
}

// ---------------------------------------------------------------- in-place LayerNorm (row=1024)
__global__ __launch_bounds__(256) void layernorm_inplace(float* __restrict__ y,
                                                         const float* __restrict__ gamma,
                                                         const float* __restrict__ beta) {
  const int row = blockIdx.x;
  float* p = y + (size_t)row * D_MODEL;
  const int tid = threadIdx.x;
  float4 v = *(const float4*)&p[tid * 4];
  float s = v.x + v.y + v.z + v.w;
  float s2 = v.x * v.x + v.y * v.y + v.z * v.z + v.w * v.w;
#pragma unroll
  for (int m = 1; m < 64; m <<= 1) {
    s += __shfl_xor(s, m);
    s2 += __shfl_xor(s2, m);
  }
  __shared__ float red[8];
  const int wave = tid >> 6, lane = tid & 63;
  if (lane == 0) { red[wave] = s; red[4 + wave] = s2; }
  __syncthreads();
  s = red[0] + red[1] + red[2] + red[3];
  s2 = red[4] + red[5] + red[6] + red[7];
  const float mu = s * (1.f / D_MODEL);
  const float var = s2 * (1.f / D_MODEL) - mu * mu;
  const float rstd = rsqrtf(var + 1e-5f);
  float4 g = *(const float4*)&gamma[tid * 4];
  float4 be = *(const float4*)&beta[tid * 4];
  float4 o;
  o.x = (v.x - mu) * rstd * g.x + be.x;
  o.y = (v.y - mu) * rstd * g.y + be.y;
  o.z = (v.z - mu) * rstd * g.z + be.z;
  o.w = (v.w - mu) * rstd * g.w + be.w;
  *(float4*)&p[tid * 4] = o;
}

// ---------------------------------------------------------------- launch
extern "C" void kernel_launch(void* const* d_in, const int* in_sizes, int n_in,
                              void* d_out, int out_size, void* d_ws, size_t ws_size,
                              hipStream_t stream) {
  (void)in_sizes; (void)n_in; (void)out_size; (void)ws_size;
  const float* x = (const float*)d_in[0];
  const float* wq = (const float*)d_in[1];
  const float* wkv = (const float*)d_in[2];
  const float* wo = (const float*)d_in[3];
  const float* gamma = (const float*)d_in[4];
  const float* beta = (const float*)d_in[5];
  float* out = (float*)d_out;

  ushort* xb = (ushort*)d_ws;                          // 8192x1024
  ushort* wb = xb + (size_t)8192 * 1024;               // 4096x1024: [wq;wkv;wo]
  ushort* qkvb = wb + (size_t)4096 * 1024;             // 8192x3072
  ushort* msgb = qkvb + (size_t)8192 * 3072;           // 8192x1024

  const int M = NBATCH * SEQ_T;  // 8192

  (void)hipFuncSetAttribute(reinterpret_cast<const void*>(&gemm1_6ph),
                            hipFuncAttributeMaxDynamicSharedMemorySize, 114688);
  (void)hipFuncSetAttribute(reinterpret_cast<const void*>(&gemm_8w<1>),
                            hipFuncAttributeMaxDynamicSharedMemorySize, 98304);

  cast_f32_bf16<<<(M * D_MODEL / 4 + 255) / 256, 256, 0, stream>>>((const float4*)x, xb, M * D_MODEL / 4);
  cast_weights<<<4096, 256, 0, stream>>>((const float4*)wq, (const float4*)wkv,
                                         (const float4*)wo, wb);

  // GEMM1: qkv = x @ [wq;wkv]^T  (M=8192, N=3072, K=1024) -> 16x32 = 512 blocks = 2.0 rounds
  gemm1_6ph<<<dim3(3072 / 192, M / 256), 512, 114688, stream>>>(xb, wb, qkvb, M, 3072, 1024);

  // windowed sigmoid attention -> msg (bf16), MFMA band formulation
  attn_win_mfma<<<dim3(SEQ_T / 64, NHEADS, NBATCH), 256, 0, stream>>>(qkvb, msgb);

  // GEMM2: y = x + msg @ wo^T  (M=8192, N=1024, K=1024) -> 8x32 = 256 blocks = 1 round
  gemm_8w<1><<<dim3(1024 / 128, M / 256), 512, 98304, stream>>>(msgb, wb + (size_t)3072 * 1024,
                                                                nullptr, out, x, M, 1024, 1024);

  // LayerNorm in place on d_out
  layernorm_inplace<<<M, 256, 0, stream>>>(out, gamma, beta);
}